// Round 1
// baseline (1842.724 us; speedup 1.0000x reference)
//
#include <hip/hip_runtime.h>
#include <math.h>

#define PI_F 3.14159265358979323846f

__device__ __forceinline__ float gelu_tanh(float x){
  float x3 = x*x*x;
  float t = tanhf(0.7978845608028654f*(x + 0.044715f*x3));
  return 0.5f*x*(1.0f+t);
}

// ---------------- group norm stats (deterministic two-pass) ----------------
// GN1: 256 channels, 32 groups of 8. One thread per channel, blocks stride positions.
__global__ __launch_bounds__(256) void gn1_partial(const float* __restrict__ x,
                                                   float* __restrict__ part, int npos){
  int c = threadIdx.x;
  float s=0.f, q=0.f;
  for(int p=blockIdx.x; p<npos; p+=gridDim.x){
    float v = x[p*256 + c];
    s += v; q += v*v;
  }
  __shared__ float ss[256], sq[256];
  ss[c]=s; sq[c]=q;
  __syncthreads();
  if((c&7)==0){
    float a=0.f,b=0.f;
    #pragma unroll
    for(int k=0;k<8;k++){ a+=ss[c+k]; b+=sq[c+k]; }
    int g=c>>3;
    part[(blockIdx.x*32+g)*2+0]=a;
    part[(blockIdx.x*32+g)*2+1]=b;
  }
}

// GN2: 512 channels, 8 groups of 64.
__global__ __launch_bounds__(256) void gn2_partial(const float* __restrict__ x,
                                                   float* __restrict__ part, int npos){
  int t=threadIdx.x;
  float s0=0.f,q0=0.f,s1=0.f,q1=0.f;
  for(int p=blockIdx.x;p<npos;p+=gridDim.x){
    float v0=x[p*512+t];
    float v1=x[p*512+256+t];
    s0+=v0;q0+=v0*v0;s1+=v1;q1+=v1*v1;
  }
  __shared__ float ss[512], sq[512];
  ss[t]=s0; sq[t]=q0; ss[t+256]=s1; sq[t+256]=q1;
  __syncthreads();
  if(t<8){
    float a=0.f,b=0.f;
    for(int k=0;k<64;k++){ a+=ss[t*64+k]; b+=sq[t*64+k]; }
    part[(blockIdx.x*8+t)*2+0]=a;
    part[(blockIdx.x*8+t)*2+1]=b;
  }
}

__global__ __launch_bounds__(64) void gn_final(const float* __restrict__ part,
                                               float* __restrict__ stats,
                                               int nblk, int ngroups, float invN){
  int g = threadIdx.x;
  if(g<ngroups){
    float s=0.f,q=0.f;
    for(int b=0;b<nblk;b++){ s+=part[(b*ngroups+g)*2+0]; q+=part[(b*ngroups+g)*2+1]; }
    float m = s*invN;
    float v = q*invN - m*m;
    stats[g*2+0]=m;
    stats[g*2+1]=rsqrtf(v+1e-5f);
  }
}

// ---------------- tiled fp32 GEMM: C = act(prolog(A) @ B + bias) ----------------
// BM=BN=128, BK=16, 256 threads, 8x8 per thread.
// PROLOG: 0=plain A, 1=group-norm on A channels (group = c >> gshift)
// ACT: 0=none, 1=gelu(tanh)
template<int PROLOG, int ACT>
__global__ __launch_bounds__(256) void gemm_k(const float* __restrict__ A,
                                              const float* __restrict__ B,
                                              const float* __restrict__ bias,
                                              float* __restrict__ C,
                                              int M, int N, int K,
                                              const float* __restrict__ gstats,
                                              const float* __restrict__ gw,
                                              const float* __restrict__ gb,
                                              int gshift)
{
  __shared__ float As[16][132];
  __shared__ float Bs[16][128];
  int row0 = blockIdx.y*128, col0 = blockIdx.x*128;
  int tid = threadIdx.x;
  int tx = tid & 15, ty = tid >> 4;
  float acc[8][8];
  #pragma unroll
  for(int i=0;i<8;i++)
    #pragma unroll
    for(int j=0;j<8;j++) acc[i][j]=0.f;

  int arow  = tid >> 1;
  int akoff = (tid & 1) * 8;
  int bkk   = tid >> 4;
  int bnoff = (tid & 15) * 8;

  for(int k0=0;k0<K;k0+=16){
    float av[8];
    int gr = row0 + arow;
    if(gr < M){
      #pragma unroll
      for(int l=0;l<8;l++){
        int c = k0 + akoff + l;
        float v = A[(size_t)gr*K + c];
        if(PROLOG==1){
          int g = c >> gshift;
          v = (v - gstats[g*2+0]) * gstats[g*2+1] * gw[c] + gb[c];
        }
        av[l]=v;
      }
    } else {
      #pragma unroll
      for(int l=0;l<8;l++) av[l]=0.f;
    }
    #pragma unroll
    for(int l=0;l<8;l++) As[akoff+l][arow]=av[l];

    float bv[8];
    {
      int gk = k0 + bkk;
      int gc = col0 + bnoff;
      const float* bp = &B[(size_t)gk*N + gc];
      #pragma unroll
      for(int l=0;l<8;l++) bv[l] = (gc+l < N) ? bp[l] : 0.f;
    }
    #pragma unroll
    for(int l=0;l<8;l++) Bs[bkk][bnoff+l]=bv[l];
    __syncthreads();

    #pragma unroll
    for(int kk=0;kk<16;kk++){
      float a[8], b[8];
      #pragma unroll
      for(int i=0;i<8;i++) a[i]=As[kk][ty*8+i];
      #pragma unroll
      for(int j=0;j<8;j++) b[j]=Bs[kk][tx*8+j];
      #pragma unroll
      for(int i=0;i<8;i++)
        #pragma unroll
        for(int j=0;j<8;j++) acc[i][j] += a[i]*b[j];
    }
    __syncthreads();
  }

  #pragma unroll
  for(int i=0;i<8;i++){
    int r = row0 + ty*8 + i;
    if(r>=M) continue;
    #pragma unroll
    for(int j=0;j<8;j++){
      int cc = col0 + tx*8 + j;
      if(cc>=N) continue;
      float v = acc[i][j];
      if(bias) v += bias[cc];
      if(ACT==1) v = gelu_tanh(v);
      C[(size_t)r*N+cc]=v;
    }
  }
}

// ---------------- latitude weights ----------------
__global__ __launch_bounds__(128) void wlat_k(const float* __restrict__ lat,
                                              float* __restrict__ w, int n){
  int i = threadIdx.x;
  if(i<n) w[i] = cosf(lat[i]);
  __syncthreads();
  if(i==0){
    float dlat = lat[1]-lat[0];
    float s4 = sinf(dlat*0.25f);
    float pw = s4*s4 / sinf(dlat*0.5f);
    if(w[0]   < 0.001f) w[0]   = pw;
    if(w[n-1] < 0.001f) w[n-1] = pw;
  }
}

// ---------------- means over lat / lon of u_mid (u2 channels 512..767) ----------------
__global__ __launch_bounds__(256) void mean_over_lat(const float* __restrict__ u2,
                                                     float* __restrict__ out){
  int lon = blockIdx.x, c = threadIdx.x;
  float s=0.f;
  for(int j=0;j<91;j++) s += u2[((size_t)(j*180+lon))*768 + 512 + c];
  out[lon*256+c] = s*(1.0f/91.0f);
}
__global__ __launch_bounds__(256) void mean_over_lon(const float* __restrict__ u2,
                                                     float* __restrict__ out){
  int latr = blockIdx.x, c = threadIdx.x;
  const float* base = u2 + (size_t)(latr*180)*768 + 512 + c;
  float s=0.f;
  for(int m=0;m<180;m++) s += base[(size_t)m*768];
  out[latr*256+c] = s*(1.0f/180.0f);
}

// ---------------- layer norm (256 channels), optional pre-scale per row ----------------
__global__ __launch_bounds__(256) void ln_k(const float* __restrict__ x,
                                            const float* __restrict__ rs,
                                            const float* __restrict__ w,
                                            const float* __restrict__ b,
                                            float* __restrict__ out){
  int r = blockIdx.x, c = threadIdx.x;
  float v = x[r*256+c];
  if(rs) v *= rs[r];
  __shared__ float red[256];
  red[c]=v; __syncthreads();
  for(int s=128;s>0;s>>=1){ if(c<s) red[c]+=red[c+s]; __syncthreads(); }
  float m = red[0]*(1.f/256.f);
  __syncthreads();
  float d = v-m;
  red[c]=d*d; __syncthreads();
  for(int s=128;s>0;s>>=1){ if(c<s) red[c]+=red[c+s]; __syncthreads(); }
  float var = red[0]*(1.f/256.f);
  out[r*256+c] = d*rsqrtf(var+1e-5f)*w[c]+b[c];
}

// ---------------- small row GEMM: out[r,j] = X[r,:256] . W[:,j] + bias ----------------
__global__ __launch_bounds__(256) void rowmm_k(const float* __restrict__ X,
                                               const float* __restrict__ W,
                                               const float* __restrict__ bias,
                                               float* __restrict__ out, int N){
  int r = blockIdx.x;
  int j = blockIdx.y*256 + threadIdx.x;
  __shared__ float xs[256];
  xs[threadIdx.x] = X[r*256 + threadIdx.x];
  __syncthreads();
  float s = bias ? bias[j] : 0.f;
  for(int c=0;c<256;c++) s += xs[c]*W[(size_t)c*N+j];
  out[(size_t)r*N+j]=s;
}

__global__ __launch_bounds__(256) void gate_k(const float* __restrict__ h,
                                              float* __restrict__ g){
  int r=blockIdx.x, j=threadIdx.x;
  float a = h[r*512+j], bb = h[r*512+256+j];
  g[r*256+j] = gelu_tanh(a)*bb;
}

// ---------------- modulation table: modU[h,m,d] = sum_k basis(d_m,k) * W[k,h,d] ----------------
__global__ __launch_bounds__(256) void modu_k(const float* __restrict__ coord,
                                              const float* __restrict__ freqs,
                                              const float* __restrict__ W,
                                              float* __restrict__ out,
                                              int nm, int nk, int periodic){
  int h = blockIdx.x / nm, m = blockIdx.x % nm;
  __shared__ float basis[64];
  int t = threadIdx.x;
  float dist = fabsf(coord[m] - coord[0]);
  if(periodic && dist > PI_F) dist = 2.f*PI_F - dist;
  float d = dist + 1e-5f;
  if(t < nk) basis[t] = 0.7978845608028654f * sinf(freqs[t]*d/PI_F) / d;
  __syncthreads();
  if(t < 192){
    float s=0.f;
    for(int k=0;k<nk;k++) s += basis[k]*W[(size_t)(k*8+h)*192+t];
    out[(size_t)(h*nm+m)*192+t]=s;
  }
}

// ---------------- low-rank kernel K[h,i,j], leaky + scales folded ----------------
__global__ __launch_bounds__(256) void lrk_k(const float* __restrict__ qry,
                                             const float* __restrict__ klk,
                                             const float* __restrict__ modu,
                                             const float* __restrict__ jscale,
                                             float* __restrict__ out,
                                             int n, float scale){
  int h = blockIdx.x / n, i = blockIdx.x % n;
  __shared__ float qs[192];
  int t=threadIdx.x;
  if(t<192) qs[t] = qry[(size_t)i*1536 + h*192 + t];
  __syncthreads();
  int j = t;
  if(j < n){
    int m = abs(i-j);
    const float* kp = &klk[(size_t)j*1536 + h*192];
    const float* mp = &modu[(size_t)(h*n + m)*192];
    float s=0.f;
    #pragma unroll 4
    for(int d=0;d<192;d++) s += qs[d]*kp[d]*mp[d];
    s = (s>=0.f) ? s : 0.2f*s;
    if(jscale) s *= jscale[j];
    out[(size_t)(h*n+i)*n + j] = s*scale;
  }
}

// ---------------- apply1: u1[h,i,m,c] = sum_j klat[h,i,j] * v_src[j,m,h,c] ----------------
// block = (h, m); stages full klat[h] (91x91) + v column (91x64) in LDS.
__global__ __launch_bounds__(256) void apply1_k(const float* __restrict__ klat,
                                                const float* __restrict__ u2,
                                                float* __restrict__ u1){
  int h = blockIdx.x / 180, m = blockIdx.x % 180;
  __shared__ float ks[91*91];
  __shared__ float vs[91*64];
  int t = threadIdx.x;
  for(int idx=t; idx<91*91; idx+=256) ks[idx] = klat[(size_t)h*8281 + idx];
  for(int idx=t; idx<91*64; idx+=256){
    int j = idx>>6, c = idx&63;
    vs[idx] = u2[(size_t)(j*180+m)*768 + h*64 + c];
  }
  __syncthreads();
  int c = t & 63;
  for(int i = t>>6; i<91; i+=4){
    const float* kp = &ks[i*91];
    float s=0.f;
    #pragma unroll 4
    for(int j=0;j<91;j++) s += kp[j]*vs[(j<<6)+c];
    u1[((size_t)(h*91+i)*180+m)*64 + c] = s;
  }
}

// ---------------- apply2: uphi[i,l,h,c] = sum_m klong[h,l,m] * u1[h,i,m,c] ----------------
// block = (h, i); stages u1[h,i] (180x64) in LDS; klong rows are wave-uniform loads (L2-hot).
__global__ __launch_bounds__(256) void apply2_k(const float* __restrict__ klong,
                                                const float* __restrict__ u1,
                                                float* __restrict__ uphi){
  int h = blockIdx.x / 91, i = blockIdx.x % 91;
  __shared__ float us[11520];
  int t = threadIdx.x;
  const float* up = u1 + (size_t)(h*91+i)*11520;
  for(int idx=t; idx<11520; idx+=256) us[idx]=up[idx];
  __syncthreads();
  int c = t & 63;
  for(int l = t>>6; l<180; l+=4){
    const float* kp = klong + (size_t)(h*180 + l)*180;
    float s=0.f;
    #pragma unroll 4
    for(int m=0;m<180;m++) s += kp[m]*us[(m<<6)+c];
    uphi[((size_t)(i*180)+l)*512 + h*64 + c] = s;
  }
}

// ---------------------------------------------------------------------------
extern "C" void kernel_launch(void* const* d_in, const int* in_sizes, int n_in,
                              void* d_out, int out_size, void* d_ws, size_t ws_size,
                              hipStream_t stream){
  const float* u_src      = (const float*)d_in[0];
  const float* u_lat_qry  = (const float*)d_in[1];
  const float* u_long_qry = (const float*)d_in[2];
  // lat/lon: robust to (src_lat,qry_lat,src_long,qry_long) vs (src_lat,src_long,...)
  const float* lat = (const float*)d_in[3];
  const float* lon = (const float*)((in_sizes[4]==180)? d_in[4] : d_in[5]);
  const float* cm_gn_w = (const float*)d_in[7];
  const float* cm_gn_b = (const float*)d_in[8];
  const float* cm_w1   = (const float*)d_in[9];
  const float* cm_b1   = (const float*)d_in[10];
  const float* cm_w2   = (const float*)d_in[11];
  const float* cm_b2   = (const float*)d_in[12];
  const float* tl_in_w = (const float*)d_in[13];
  const float* tl_ln_w = (const float*)d_in[14];
  const float* tl_ln_b = (const float*)d_in[15];
  const float* tl_w1   = (const float*)d_in[16];
  const float* tl_b1   = (const float*)d_in[17];
  const float* tl_w2   = (const float*)d_in[18];
  const float* tl_b2   = (const float*)d_in[19];
  const float* ta_in_w = (const float*)d_in[20];
  const float* ta_ln_w = (const float*)d_in[21];
  const float* ta_ln_b = (const float*)d_in[22];
  const float* ta_w1   = (const float*)d_in[23];
  const float* ta_b1   = (const float*)d_in[24];
  const float* ta_w2   = (const float*)d_in[25];
  const float* ta_b2   = (const float*)d_in[26];
  const float* klong_wk= (const float*)d_in[27];
  const float* klat_wk = (const float*)d_in[28];
  const float* pe_long_freq = (const float*)d_in[29];
  const float* pe_long_w    = (const float*)d_in[30];
  const float* pe_lat_freq  = (const float*)d_in[31];
  const float* pe_lat_w     = (const float*)d_in[32];
  const float* mh_gn_w = (const float*)d_in[33];
  const float* mh_gn_b = (const float*)d_in[34];
  const float* mh_w    = (const float*)d_in[35];

  float* ws = (float*)d_ws;
  // ---- workspace layout (float offsets). Peak ~126 MB with h1 region reuse. ----
  const size_t OFF_PART1  = 0;          // 15360
  const size_t OFF_GN1    = 16384;      // 64
  const size_t OFF_WLAT   = 16512;      // 91
  const size_t OFF_MEANLAT= 16640;      // 46080
  const size_t OFF_MEANLON= 62720;      // 23296
  const size_t OFF_YLONG  = 86016;      // 46080
  const size_t OFF_YLAT   = 132096;     // 23296
  const size_t OFF_LNLONG = 155392;     // 46080
  const size_t OFF_LNLAT  = 201472;     // 23296
  const size_t OFF_HLONG  = 224768;     // 92160
  const size_t OFF_HLAT   = 316928;     // 46592
  const size_t OFF_GLONG  = 363520;     // 46080
  const size_t OFF_GLAT   = 409600;     // 23296
  const size_t OFF_ULSRC  = 432896;     // 46080
  const size_t OFF_UASRC  = 478976;     // 23296
  const size_t OFF_KLKL   = 502272;     // 276480
  const size_t OFF_KLKA   = 778752;     // 139776
  const size_t OFF_MODUL  = 918528;     // 276480
  const size_t OFF_MODUA  = 1195008;    // 139776
  const size_t OFF_KL     = 1334784;    // 259200
  const size_t OFF_KA     = 1593984;    // 66248
  const size_t OFF_PART2  = 1660928;    // 3840
  const size_t OFF_GN2    = 1664768;    // 16
  const size_t OFF_H1     = 2097152;    // 16773120 (dead after u2 GEMM)
  const size_t OFF_U1     = 2097152;    // 8386560  (reuses h1 region)
  const size_t OFF_UPHI2  = 10485760;   // 8386560
  const size_t OFF_U2     = 18874368;   // 12579840 -> ends at ~125.8 MB

  const int NPOS = 16380;

  // 1) GN1 stats (global, per 32 groups)
  gn1_partial<<<240,256,0,stream>>>(u_src, ws+OFF_PART1, NPOS);
  gn_final<<<1,64,0,stream>>>(ws+OFF_PART1, ws+OFF_GN1, 240, 32, 1.f/131040.f);

  // 2) h1 = gelu(GN(u_src) @ cm_w1 + cm_b1)   [16380 x 1024]
  gemm_k<1,1><<<dim3(8,128),256,0,stream>>>(u_src, cm_w1, cm_b1, ws+OFF_H1,
      NPOS, 1024, 256, ws+OFF_GN1, cm_gn_w, cm_gn_b, 3);

  // 3) u2 = h1 @ cm_w2 + cm_b2   [16380 x 768]  (v_src = [:512], u_mid = [512:])
  gemm_k<0,0><<<dim3(6,128),256,0,stream>>>(ws+OFF_H1, cm_w2, cm_b2, ws+OFF_U2,
      NPOS, 768, 1024, nullptr, nullptr, nullptr, 0);

  // 4) latitude weights
  wlat_k<<<1,128,0,stream>>>(lat, ws+OFF_WLAT, 91);

  // 5) pooling means (mean commutes with the channel matmul)
  mean_over_lat<<<180,256,0,stream>>>(ws+OFF_U2, ws+OFF_MEANLAT);
  mean_over_lon<<<91,256,0,stream>>>(ws+OFF_U2, ws+OFF_MEANLON);

  // 6) y = mean @ in_w  (wlat scale applied pre-LN inside ln_k)
  gemm_k<0,0><<<dim3(2,2),256,0,stream>>>(ws+OFF_MEANLAT, tl_in_w, nullptr, ws+OFF_YLONG,
      180, 256, 256, nullptr, nullptr, nullptr, 0);
  gemm_k<0,0><<<dim3(2,1),256,0,stream>>>(ws+OFF_MEANLON, ta_in_w, nullptr, ws+OFF_YLAT,
      91, 256, 256, nullptr, nullptr, nullptr, 0);

  // 7) gated MLPs
  ln_k<<<180,256,0,stream>>>(ws+OFF_YLONG, nullptr,     tl_ln_w, tl_ln_b, ws+OFF_LNLONG);
  ln_k<<<91,256,0,stream>>>(ws+OFF_YLAT,  ws+OFF_WLAT, ta_ln_w, ta_ln_b, ws+OFF_LNLAT);
  rowmm_k<<<dim3(180,2),256,0,stream>>>(ws+OFF_LNLONG, tl_w1, tl_b1, ws+OFF_HLONG, 512);
  rowmm_k<<<dim3(91,2),256,0,stream>>>(ws+OFF_LNLAT,  ta_w1, ta_b1, ws+OFF_HLAT, 512);
  gate_k<<<180,256,0,stream>>>(ws+OFF_HLONG, ws+OFF_GLONG);
  gate_k<<<91,256,0,stream>>>(ws+OFF_HLAT,  ws+OFF_GLAT);
  rowmm_k<<<dim3(180,1),256,0,stream>>>(ws+OFF_GLONG, tl_w2, tl_b2, ws+OFF_ULSRC, 256);
  rowmm_k<<<dim3(91,1),256,0,stream>>>(ws+OFF_GLAT,  ta_w2, ta_b2, ws+OFF_UASRC, 256);

  // 8) k-projections: u_src_pooled @ wk  -> [*,1536]
  gemm_k<0,0><<<dim3(12,2),256,0,stream>>>(ws+OFF_ULSRC, klong_wk, nullptr, ws+OFF_KLKL,
      180, 1536, 256, nullptr, nullptr, nullptr, 0);
  gemm_k<0,0><<<dim3(12,1),256,0,stream>>>(ws+OFF_UASRC, klat_wk, nullptr, ws+OFF_KLKA,
      91, 1536, 256, nullptr, nullptr, nullptr, 0);

  // 9) modulation tables — only |i-j| distinct distances on uniform grids
  modu_k<<<8*180,192,0,stream>>>(lon, pe_long_freq, pe_long_w, ws+OFF_MODUL, 180, 64, 1);
  modu_k<<<8*91, 192,0,stream>>>(lat, pe_lat_freq,  pe_lat_w,  ws+OFF_MODUA, 91, 32, 0);

  // 10) low-rank kernels (leaky + quadrature scale + wlat folded in)
  lrk_k<<<8*180,256,0,stream>>>(u_long_qry, ws+OFF_KLKL, ws+OFF_MODUL, nullptr,
      ws+OFF_KL, 180, 2.f*PI_F/180.f);
  lrk_k<<<8*91, 256,0,stream>>>(u_lat_qry,  ws+OFF_KLKA, ws+OFF_MODUA, ws+OFF_WLAT,
      ws+OFF_KA, 91, PI_F/91.f);

  // 11) kernel application
  apply1_k<<<8*180,256,0,stream>>>(ws+OFF_KA, ws+OFF_U2, ws+OFF_U1);
  apply2_k<<<8*91, 256,0,stream>>>(ws+OFF_KL, ws+OFF_U1, ws+OFF_UPHI2);

  // 12) GN2 + final projection
  gn2_partial<<<240,256,0,stream>>>(ws+OFF_UPHI2, ws+OFF_PART2, NPOS);
  gn_final<<<1,64,0,stream>>>(ws+OFF_PART2, ws+OFF_GN2, 240, 8, 1.f/1048320.f);
  gemm_k<1,0><<<dim3(2,128),256,0,stream>>>(ws+OFF_UPHI2, mh_w, nullptr, (float*)d_out,
      NPOS, 256, 512, ws+OFF_GN2, mh_gn_w, mh_gn_b, 6);
}

// Round 2
// 1237.614 us; speedup vs baseline: 1.4889x; 1.4889x over previous
//
#include <hip/hip_runtime.h>
#include <math.h>

#define PI_F 3.14159265358979323846f

typedef __bf16  bf16x8  __attribute__((ext_vector_type(8)));
typedef float   floatx4 __attribute__((ext_vector_type(4)));

__device__ __forceinline__ float gelu_tanh(float x){
  float x3 = x*x*x;
  float t = tanhf(0.7978845608028654f*(x + 0.044715f*x3));
  return 0.5f*x*(1.0f+t);
}

// ---------------- group norm stats (deterministic two-pass) ----------------
__global__ __launch_bounds__(256) void gn1_partial(const float* __restrict__ x,
                                                   float* __restrict__ part, int npos){
  int c = threadIdx.x;
  float s=0.f, q=0.f;
  for(int p=blockIdx.x; p<npos; p+=gridDim.x){
    float v = x[p*256 + c];
    s += v; q += v*v;
  }
  __shared__ float ss[256], sq[256];
  ss[c]=s; sq[c]=q;
  __syncthreads();
  if((c&7)==0){
    float a=0.f,b=0.f;
    #pragma unroll
    for(int k=0;k<8;k++){ a+=ss[c+k]; b+=sq[c+k]; }
    int g=c>>3;
    part[(blockIdx.x*32+g)*2+0]=a;
    part[(blockIdx.x*32+g)*2+1]=b;
  }
}

__global__ __launch_bounds__(256) void gn2_partial(const float* __restrict__ x,
                                                   float* __restrict__ part, int npos){
  int t=threadIdx.x;
  float s0=0.f,q0=0.f,s1=0.f,q1=0.f;
  for(int p=blockIdx.x;p<npos;p+=gridDim.x){
    float v0=x[p*512+t];
    float v1=x[p*512+256+t];
    s0+=v0;q0+=v0*v0;s1+=v1;q1+=v1*v1;
  }
  __shared__ float ss[512], sq[512];
  ss[t]=s0; sq[t]=q0; ss[t+256]=s1; sq[t+256]=q1;
  __syncthreads();
  if(t<8){
    float a=0.f,b=0.f;
    for(int k=0;k<64;k++){ a+=ss[t*64+k]; b+=sq[t*64+k]; }
    part[(blockIdx.x*8+t)*2+0]=a;
    part[(blockIdx.x*8+t)*2+1]=b;
  }
}

__global__ __launch_bounds__(64) void gn_final(const float* __restrict__ part,
                                               float* __restrict__ stats,
                                               int nblk, int ngroups, float invN){
  int g = threadIdx.x;
  if(g<ngroups){
    float s=0.f,q=0.f;
    for(int b=0;b<nblk;b++){ s+=part[(b*ngroups+g)*2+0]; q+=part[(b*ngroups+g)*2+1]; }
    float m = s*invN;
    float v = q*invN - m*m;
    stats[g*2+0]=m;
    stats[g*2+1]=rsqrtf(v+1e-5f);
  }
}

// ---------------- weight transpose+convert: out[n][k] = bf16(in[k][n]) ----------------
__global__ __launch_bounds__(256) void wcvt_k(const float* __restrict__ in,
                                              __bf16* __restrict__ out, int K, int N){
  int idx = blockIdx.x*256 + threadIdx.x;
  if(idx < N*K){
    int n = idx / K, k = idx - n*K;
    out[idx] = (__bf16)in[(size_t)k*N + n];
  }
}

// ---------------- MFMA bf16 GEMM ----------------
// C[M,N] = act( prolog(A)[M,K] @ B[K,N] + bias )
// A: AMODE 0 = bf16 row-major MxK; AMODE 1 = fp32 MxK with fused group-norm.
// B passed TRANSPOSED bf16 [N][K]. 128x128 tile, BK=32, 4 waves (2x2), 4x4
// 16x16x32 MFMA tiles per wave. LDS rows padded to 40 halfwords (bank spread).
template<int AMODE, int ACT, int CBF16>
__global__ __launch_bounds__(256) void gemm_mfma(const void* __restrict__ Aip,
                                                 const __bf16* __restrict__ Bt,
                                                 const float* __restrict__ bias,
                                                 void* __restrict__ Cp,
                                                 int M, int N, int K,
                                                 const float* __restrict__ gstats,
                                                 const float* __restrict__ gw,
                                                 const float* __restrict__ gb,
                                                 int gshift)
{
  __shared__ __bf16 As[128][40];
  __shared__ __bf16 Bs[128][40];
  const int tid  = threadIdx.x;
  const int row0 = blockIdx.y*128, col0 = blockIdx.x*128;
  const int r = tid & 127, h = tid >> 7;        // staging: row, 16-col half
  const int lane = tid & 63, wave = tid >> 6;
  const int wr = (wave >> 1)*64, wc = (wave & 1)*64;
  const int m16 = lane & 15, quad = lane >> 4;

  floatx4 acc[4][4];
  #pragma unroll
  for(int i=0;i<4;i++)
    #pragma unroll
    for(int j=0;j<4;j++) acc[i][j] = (floatx4)0.f;

  const int agr = row0 + r;
  for(int k0=0; k0<K; k0+=32){
    // ---- stage A ----
    {
      __bf16 av[16];
      if(agr < M){
        if(AMODE==0){
          const __bf16* ap = (const __bf16*)Aip + (size_t)agr*K + k0 + h*16;
          bf16x8 v0 = *(const bf16x8*)ap;
          bf16x8 v1 = *(const bf16x8*)(ap+8);
          #pragma unroll
          for(int l=0;l<8;l++){ av[l]=v0[l]; av[8+l]=v1[l]; }
        } else {
          const float* ap = (const float*)Aip + (size_t)agr*K + k0 + h*16;
          #pragma unroll
          for(int l=0;l<16;l++){
            int c = k0 + h*16 + l;
            int g = c >> gshift;
            float v = (ap[l] - gstats[g*2+0]) * gstats[g*2+1] * gw[c] + gb[c];
            av[l] = (__bf16)v;
          }
        }
      } else {
        #pragma unroll
        for(int l=0;l<16;l++) av[l] = (__bf16)0.f;
      }
      bf16x8 w0, w1;
      #pragma unroll
      for(int l=0;l<8;l++){ w0[l]=av[l]; w1[l]=av[8+l]; }
      *(bf16x8*)&As[r][h*16]     = w0;
      *(bf16x8*)&As[r][h*16 + 8] = w1;
    }
    // ---- stage B (already [N][K]) ----
    {
      const __bf16* bp = Bt + (size_t)(col0 + r)*K + k0 + h*16;
      *(bf16x8*)&Bs[r][h*16]     = *(const bf16x8*)bp;
      *(bf16x8*)&Bs[r][h*16 + 8] = *(const bf16x8*)(bp+8);
    }
    __syncthreads();

    bf16x8 af[4], bfv[4];
    #pragma unroll
    for(int ti=0;ti<4;ti++) af[ti]  = *(const bf16x8*)&As[wr + ti*16 + m16][quad*8];
    #pragma unroll
    for(int tj=0;tj<4;tj++) bfv[tj] = *(const bf16x8*)&Bs[wc + tj*16 + m16][quad*8];
    #pragma unroll
    for(int ti=0;ti<4;ti++)
      #pragma unroll
      for(int tj=0;tj<4;tj++)
        acc[ti][tj] = __builtin_amdgcn_mfma_f32_16x16x32_bf16(af[ti], bfv[tj], acc[ti][tj], 0,0,0);
    __syncthreads();
  }

  // ---- epilogue: C/D layout col=lane&15, row=quad*4+reg ----
  #pragma unroll
  for(int ti=0;ti<4;ti++){
    #pragma unroll
    for(int reg=0;reg<4;reg++){
      int gr = row0 + wr + ti*16 + quad*4 + reg;
      if(gr >= M) continue;
      #pragma unroll
      for(int tj=0;tj<4;tj++){
        int gc = col0 + wc + tj*16 + m16;
        float v = acc[ti][tj][reg];
        if(bias) v += bias[gc];
        if(ACT==1) v = gelu_tanh(v);
        if(CBF16) ((__bf16*)Cp)[(size_t)gr*N + gc] = (__bf16)v;
        else      ((float*)Cp)[(size_t)gr*N + gc]  = v;
      }
    }
  }
}

// ---------------- latitude weights ----------------
__global__ __launch_bounds__(128) void wlat_k(const float* __restrict__ lat,
                                              float* __restrict__ w, int n){
  int i = threadIdx.x;
  if(i<n) w[i] = cosf(lat[i]);
  __syncthreads();
  if(i==0){
    float dlat = lat[1]-lat[0];
    float s4 = sinf(dlat*0.25f);
    float pw = s4*s4 / sinf(dlat*0.5f);
    if(w[0]   < 0.001f) w[0]   = pw;
    if(w[n-1] < 0.001f) w[n-1] = pw;
  }
}

// ---------------- means over lat / lon of u_mid (u2 channels 512..767) ----------------
__global__ __launch_bounds__(256) void mean_over_lat(const float* __restrict__ u2,
                                                     float* __restrict__ out){
  int lon = blockIdx.x, c = threadIdx.x;
  float s=0.f;
  for(int j=0;j<91;j++) s += u2[((size_t)(j*180+lon))*768 + 512 + c];
  out[lon*256+c] = s*(1.0f/91.0f);
}
__global__ __launch_bounds__(256) void mean_over_lon(const float* __restrict__ u2,
                                                     float* __restrict__ out){
  int latr = blockIdx.x, c = threadIdx.x;
  const float* base = u2 + (size_t)(latr*180)*768 + 512 + c;
  float s=0.f;
  for(int m=0;m<180;m++) s += base[(size_t)m*768];
  out[latr*256+c] = s*(1.0f/180.0f);
}

// ---------------- layer norm (256 ch), optional per-row pre-scale ----------------
__global__ __launch_bounds__(256) void ln_k(const float* __restrict__ x,
                                            const float* __restrict__ rs,
                                            const float* __restrict__ w,
                                            const float* __restrict__ b,
                                            float* __restrict__ out){
  int r = blockIdx.x, c = threadIdx.x;
  float v = x[r*256+c];
  if(rs) v *= rs[r];
  __shared__ float red[256];
  red[c]=v; __syncthreads();
  for(int s=128;s>0;s>>=1){ if(c<s) red[c]+=red[c+s]; __syncthreads(); }
  float m = red[0]*(1.f/256.f);
  __syncthreads();
  float d = v-m;
  red[c]=d*d; __syncthreads();
  for(int s=128;s>0;s>>=1){ if(c<s) red[c]+=red[c+s]; __syncthreads(); }
  float var = red[0]*(1.f/256.f);
  out[r*256+c] = d*rsqrtf(var+1e-5f)*w[c]+b[c];
}

// ---------------- small row GEMM ----------------
__global__ __launch_bounds__(256) void rowmm_k(const float* __restrict__ X,
                                               const float* __restrict__ W,
                                               const float* __restrict__ bias,
                                               float* __restrict__ out, int N){
  int r = blockIdx.x;
  int j = blockIdx.y*256 + threadIdx.x;
  __shared__ float xs[256];
  xs[threadIdx.x] = X[r*256 + threadIdx.x];
  __syncthreads();
  float s = bias ? bias[j] : 0.f;
  for(int c=0;c<256;c++) s += xs[c]*W[(size_t)c*N+j];
  out[(size_t)r*N+j]=s;
}

__global__ __launch_bounds__(256) void gate_k(const float* __restrict__ h,
                                              float* __restrict__ g){
  int r=blockIdx.x, j=threadIdx.x;
  float a = h[r*512+j], bb = h[r*512+256+j];
  g[r*256+j] = gelu_tanh(a)*bb;
}

// ---------------- modulation table ----------------
__global__ __launch_bounds__(256) void modu_k(const float* __restrict__ coord,
                                              const float* __restrict__ freqs,
                                              const float* __restrict__ W,
                                              float* __restrict__ out,
                                              int nm, int nk, int periodic){
  int h = blockIdx.x / nm, m = blockIdx.x % nm;
  __shared__ float basis[64];
  int t = threadIdx.x;
  float dist = fabsf(coord[m] - coord[0]);
  if(periodic && dist > PI_F) dist = 2.f*PI_F - dist;
  float d = dist + 1e-5f;
  if(t < nk) basis[t] = 0.7978845608028654f * sinf(freqs[t]*d/PI_F) / d;
  __syncthreads();
  if(t < 192){
    float s=0.f;
    for(int k=0;k<nk;k++) s += basis[k]*W[(size_t)(k*8+h)*192+t];
    out[(size_t)(h*nm+m)*192+t]=s;
  }
}

// ---------------- low-rank kernel ----------------
__global__ __launch_bounds__(256) void lrk_k(const float* __restrict__ qry,
                                             const float* __restrict__ klk,
                                             const float* __restrict__ modu,
                                             const float* __restrict__ jscale,
                                             float* __restrict__ out,
                                             int n, float scale){
  int h = blockIdx.x / n, i = blockIdx.x % n;
  __shared__ float qs[192];
  int t=threadIdx.x;
  if(t<192) qs[t] = qry[(size_t)i*1536 + h*192 + t];
  __syncthreads();
  int j = t;
  if(j < n){
    int m = abs(i-j);
    const float* kp = &klk[(size_t)j*1536 + h*192];
    const float* mp = &modu[(size_t)(h*n + m)*192];
    float s=0.f;
    #pragma unroll 4
    for(int d=0;d<192;d++) s += qs[d]*kp[d]*mp[d];
    s = (s>=0.f) ? s : 0.2f*s;
    if(jscale) s *= jscale[j];
    out[(size_t)(h*n+i)*n + j] = s*scale;
  }
}

// ---------------- apply1: u1[h,i,m,c] = sum_j klat[h,i,j] * v_src[j,m,h,c] ----------------
__global__ __launch_bounds__(256) void apply1_k(const float* __restrict__ klat,
                                                const float* __restrict__ u2,
                                                float* __restrict__ u1){
  int h = blockIdx.x / 180, m = blockIdx.x % 180;
  __shared__ float ks[91*91];
  __shared__ float vs[91*64];
  int t = threadIdx.x;
  for(int idx=t; idx<91*91; idx+=256) ks[idx] = klat[(size_t)h*8281 + idx];
  for(int idx=t; idx<91*64; idx+=256){
    int j = idx>>6, c = idx&63;
    vs[idx] = u2[(size_t)(j*180+m)*768 + h*64 + c];
  }
  __syncthreads();
  int c = t & 63;
  for(int i = t>>6; i<91; i+=4){
    const float* kp = &ks[i*91];
    float s=0.f;
    #pragma unroll 4
    for(int j=0;j<91;j++) s += kp[j]*vs[(j<<6)+c];
    u1[((size_t)(h*91+i)*180+m)*64 + c] = s;
  }
}

// ---------------- apply2: uphi[i,l,h,c] = sum_m klong[h,l,m] * u1[h,i,m,c] ----------------
__global__ __launch_bounds__(256) void apply2_k(const float* __restrict__ klong,
                                                const float* __restrict__ u1,
                                                float* __restrict__ uphi){
  int h = blockIdx.x / 91, i = blockIdx.x % 91;
  __shared__ float us[11520];
  int t = threadIdx.x;
  const float* up = u1 + (size_t)(h*91+i)*11520;
  for(int idx=t; idx<11520; idx+=256) us[idx]=up[idx];
  __syncthreads();
  int c = t & 63;
  for(int l = t>>6; l<180; l+=4){
    const float* kp = klong + (size_t)(h*180 + l)*180;
    float s=0.f;
    #pragma unroll 4
    for(int m=0;m<180;m++) s += kp[m]*us[(m<<6)+c];
    uphi[((size_t)(i*180)+l)*512 + h*64 + c] = s;
  }
}

// ---------------------------------------------------------------------------
extern "C" void kernel_launch(void* const* d_in, const int* in_sizes, int n_in,
                              void* d_out, int out_size, void* d_ws, size_t ws_size,
                              hipStream_t stream){
  const float* u_src      = (const float*)d_in[0];
  const float* u_lat_qry  = (const float*)d_in[1];
  const float* u_long_qry = (const float*)d_in[2];
  const float* lat = (const float*)d_in[3];
  const float* lon = (const float*)((in_sizes[4]==180)? d_in[4] : d_in[5]);
  const float* cm_gn_w = (const float*)d_in[7];
  const float* cm_gn_b = (const float*)d_in[8];
  const float* cm_w1   = (const float*)d_in[9];
  const float* cm_b1   = (const float*)d_in[10];
  const float* cm_w2   = (const float*)d_in[11];
  const float* cm_b2   = (const float*)d_in[12];
  const float* tl_in_w = (const float*)d_in[13];
  const float* tl_ln_w = (const float*)d_in[14];
  const float* tl_ln_b = (const float*)d_in[15];
  const float* tl_w1   = (const float*)d_in[16];
  const float* tl_b1   = (const float*)d_in[17];
  const float* tl_w2   = (const float*)d_in[18];
  const float* tl_b2   = (const float*)d_in[19];
  const float* ta_in_w = (const float*)d_in[20];
  const float* ta_ln_w = (const float*)d_in[21];
  const float* ta_ln_b = (const float*)d_in[22];
  const float* ta_w1   = (const float*)d_in[23];
  const float* ta_b1   = (const float*)d_in[24];
  const float* ta_w2   = (const float*)d_in[25];
  const float* ta_b2   = (const float*)d_in[26];
  const float* klong_wk= (const float*)d_in[27];
  const float* klat_wk = (const float*)d_in[28];
  const float* pe_long_freq = (const float*)d_in[29];
  const float* pe_long_w    = (const float*)d_in[30];
  const float* pe_lat_freq  = (const float*)d_in[31];
  const float* pe_lat_w     = (const float*)d_in[32];
  const float* mh_gn_w = (const float*)d_in[33];
  const float* mh_gn_b = (const float*)d_in[34];
  const float* mh_w    = (const float*)d_in[35];

  float* ws = (float*)d_ws;
  // ---- workspace layout (float offsets). Peak ~93 MB. ----
  const size_t OFF_PART1  = 0;          // 15360
  const size_t OFF_GN1    = 16384;      // 64
  const size_t OFF_WLAT   = 16512;      // 91
  const size_t OFF_MEANLAT= 16640;      // 46080
  const size_t OFF_MEANLON= 62720;      // 23296
  const size_t OFF_YLONG  = 86016;      // 46080
  const size_t OFF_YLAT   = 132096;     // 23296
  const size_t OFF_LNLONG = 155392;     // 46080
  const size_t OFF_LNLAT  = 201472;     // 23296
  const size_t OFF_HLONG  = 224768;     // 92160
  const size_t OFF_HLAT   = 316928;     // 46592
  const size_t OFF_GLONG  = 363520;     // 46080
  const size_t OFF_GLAT   = 409600;     // 23296
  const size_t OFF_ULSRC  = 432896;     // 46080
  const size_t OFF_UASRC  = 478976;     // 23296
  const size_t OFF_KLKL   = 502272;     // 276480
  const size_t OFF_KLKA   = 778752;     // 139776
  const size_t OFF_MODUL  = 918528;     // 276480
  const size_t OFF_MODUA  = 1195008;    // 139776
  const size_t OFF_KL     = 1334784;    // 259200
  const size_t OFF_KA     = 1593984;    // 66248
  const size_t OFF_PART2  = 1660928;    // 3840
  const size_t OFF_GN2    = 1664768;    // 16
  // bf16 transposed weights (sizes in float-equivalents: bf16 count / 2)
  const size_t OFF_WT1    = 1703936;    // cm_w1^T  1024x256 bf16 -> 131072
  const size_t OFF_WT2    = 1835008;    // cm_w2^T  768x1024 bf16 -> 393216
  const size_t OFF_WT3    = 2228224;    // mh_w^T   256x512  bf16 -> 65536
  // big buffers with reuse:
  const size_t OFF_U2     = 2359296;    // fp32 16380x768  = 12579840 -> ends 14939136
  const size_t OFF_H1     = 14939136;   // bf16 16380x1024 = 8386560 f-equiv -> ends 23325696
  const size_t OFF_U1     = 14939136;   // fp32 8386560, reuses h1 (dead after u2 GEMM)
  const size_t OFF_UPHI2  = 2359296;    // fp32 8386560, reuses u2 (dead after apply1)

  const int NPOS = 16380;

  // 0) weight transpose+convert to bf16 [N][K]
  wcvt_k<<<(256*1024+255)/256,256,0,stream>>>(cm_w1, (__bf16*)(ws+OFF_WT1), 256, 1024);
  wcvt_k<<<(1024*768+255)/256,256,0,stream>>>(cm_w2, (__bf16*)(ws+OFF_WT2), 1024, 768);
  wcvt_k<<<(512*256+255)/256,256,0,stream>>>(mh_w,  (__bf16*)(ws+OFF_WT3), 512, 256);

  // 1) GN1 stats
  gn1_partial<<<240,256,0,stream>>>(u_src, ws+OFF_PART1, NPOS);
  gn_final<<<1,64,0,stream>>>(ws+OFF_PART1, ws+OFF_GN1, 240, 32, 1.f/131040.f);

  // 2) h1 = gelu(GN(u_src) @ cm_w1 + cm_b1)  [16380 x 1024] bf16, MFMA
  gemm_mfma<1,1,1><<<dim3(8,128),256,0,stream>>>(u_src, (__bf16*)(ws+OFF_WT1), cm_b1,
      ws+OFF_H1, NPOS, 1024, 256, ws+OFF_GN1, cm_gn_w, cm_gn_b, 3);

  // 3) u2 = h1 @ cm_w2 + cm_b2  [16380 x 768] fp32, MFMA
  gemm_mfma<0,0,0><<<dim3(6,128),256,0,stream>>>(ws+OFF_H1, (__bf16*)(ws+OFF_WT2), cm_b2,
      ws+OFF_U2, NPOS, 768, 1024, nullptr, nullptr, nullptr, 0);

  // 4) latitude weights
  wlat_k<<<1,128,0,stream>>>(lat, ws+OFF_WLAT, 91);

  // 5) pooling means
  mean_over_lat<<<180,256,0,stream>>>(ws+OFF_U2, ws+OFF_MEANLAT);
  mean_over_lon<<<91,256,0,stream>>>(ws+OFF_U2, ws+OFF_MEANLON);

  // 6) y = mean @ in_w  (fp32 small GEMM path)
  rowmm_k<<<dim3(180,1),256,0,stream>>>(ws+OFF_MEANLAT, tl_in_w, nullptr, ws+OFF_YLONG, 256);
  rowmm_k<<<dim3(91,1), 256,0,stream>>>(ws+OFF_MEANLON, ta_in_w, nullptr, ws+OFF_YLAT, 256);

  // 7) gated MLPs
  ln_k<<<180,256,0,stream>>>(ws+OFF_YLONG, nullptr,     tl_ln_w, tl_ln_b, ws+OFF_LNLONG);
  ln_k<<<91,256,0,stream>>>(ws+OFF_YLAT,  ws+OFF_WLAT, ta_ln_w, ta_ln_b, ws+OFF_LNLAT);
  rowmm_k<<<dim3(180,2),256,0,stream>>>(ws+OFF_LNLONG, tl_w1, tl_b1, ws+OFF_HLONG, 512);
  rowmm_k<<<dim3(91,2), 256,0,stream>>>(ws+OFF_LNLAT,  ta_w1, ta_b1, ws+OFF_HLAT, 512);
  gate_k<<<180,256,0,stream>>>(ws+OFF_HLONG, ws+OFF_GLONG);
  gate_k<<<91,256,0,stream>>>(ws+OFF_HLAT,  ws+OFF_GLAT);
  rowmm_k<<<dim3(180,1),256,0,stream>>>(ws+OFF_GLONG, tl_w2, tl_b2, ws+OFF_ULSRC, 256);
  rowmm_k<<<dim3(91,1), 256,0,stream>>>(ws+OFF_GLAT,  ta_w2, ta_b2, ws+OFF_UASRC, 256);

  // 8) k-projections
  rowmm_k<<<dim3(180,6),256,0,stream>>>(ws+OFF_ULSRC, klong_wk, nullptr, ws+OFF_KLKL, 1536);
  rowmm_k<<<dim3(91,6), 256,0,stream>>>(ws+OFF_UASRC, klat_wk, nullptr, ws+OFF_KLKA, 1536);

  // 9) modulation tables (|i-j| distinct distances only)
  modu_k<<<8*180,192,0,stream>>>(lon, pe_long_freq, pe_long_w, ws+OFF_MODUL, 180, 64, 1);
  modu_k<<<8*91, 192,0,stream>>>(lat, pe_lat_freq,  pe_lat_w,  ws+OFF_MODUA, 91, 32, 0);

  // 10) low-rank kernels
  lrk_k<<<8*180,256,0,stream>>>(u_long_qry, ws+OFF_KLKL, ws+OFF_MODUL, nullptr,
      ws+OFF_KL, 180, 2.f*PI_F/180.f);
  lrk_k<<<8*91, 256,0,stream>>>(u_lat_qry,  ws+OFF_KLKA, ws+OFF_MODUA, ws+OFF_WLAT,
      ws+OFF_KA, 91, PI_F/91.f);

  // 11) kernel application
  apply1_k<<<8*180,256,0,stream>>>(ws+OFF_KA, ws+OFF_U2, ws+OFF_U1);
  apply2_k<<<8*91, 256,0,stream>>>(ws+OFF_KL, ws+OFF_U1, ws+OFF_UPHI2);

  // 12) GN2 + final projection (MFMA)
  gn2_partial<<<240,256,0,stream>>>(ws+OFF_UPHI2, ws+OFF_PART2, NPOS);
  gn_final<<<1,64,0,stream>>>(ws+OFF_PART2, ws+OFF_GN2, 240, 8, 1.f/1048320.f);
  gemm_mfma<1,0,0><<<dim3(2,128),256,0,stream>>>(ws+OFF_UPHI2, (__bf16*)(ws+OFF_WT3), nullptr,
      (float*)d_out, NPOS, 256, 512, ws+OFF_GN2, mh_gn_w, mh_gn_b, 6);
}

// Round 3
// 812.113 us; speedup vs baseline: 2.2690x; 1.5239x over previous
//
#include <hip/hip_runtime.h>
#include <math.h>

#define PI_F 3.14159265358979323846f

typedef __bf16  bf16x8  __attribute__((ext_vector_type(8)));
typedef float   floatx4 __attribute__((ext_vector_type(4)));

__device__ __forceinline__ float gelu_tanh(float x){
  float x3 = x*x*x;
  float t = tanhf(0.7978845608028654f*(x + 0.044715f*x3));
  return 0.5f*x*(1.0f+t);
}

// ---------------- group norm stats (deterministic two-pass) ----------------
__global__ __launch_bounds__(256) void gn1_partial(const float* __restrict__ x,
                                                   float* __restrict__ part, int npos){
  int c = threadIdx.x;
  float s=0.f, q=0.f;
  for(int p=blockIdx.x; p<npos; p+=gridDim.x){
    float v = x[p*256 + c];
    s += v; q += v*v;
  }
  __shared__ float ss[256], sq[256];
  ss[c]=s; sq[c]=q;
  __syncthreads();
  if((c&7)==0){
    float a=0.f,b=0.f;
    #pragma unroll
    for(int k=0;k<8;k++){ a+=ss[c+k]; b+=sq[c+k]; }
    int g=c>>3;
    part[(blockIdx.x*32+g)*2+0]=a;
    part[(blockIdx.x*32+g)*2+1]=b;
  }
}

__global__ __launch_bounds__(256) void gn2_partial(const float* __restrict__ x,
                                                   float* __restrict__ part, int npos){
  int t=threadIdx.x;
  float s0=0.f,q0=0.f,s1=0.f,q1=0.f;
  for(int p=blockIdx.x;p<npos;p+=gridDim.x){
    float v0=x[p*512+t];
    float v1=x[p*512+256+t];
    s0+=v0;q0+=v0*v0;s1+=v1;q1+=v1*v1;
  }
  __shared__ float ss[512], sq[512];
  ss[t]=s0; sq[t]=q0; ss[t+256]=s1; sq[t+256]=q1;
  __syncthreads();
  if(t<8){
    float a=0.f,b=0.f;
    for(int k=0;k<64;k++){ a+=ss[t*64+k]; b+=sq[t*64+k]; }
    part[(blockIdx.x*8+t)*2+0]=a;
    part[(blockIdx.x*8+t)*2+1]=b;
  }
}

__global__ __launch_bounds__(64) void gn_final(const float* __restrict__ part,
                                               float* __restrict__ stats,
                                               int nblk, int ngroups, float invN){
  int g = threadIdx.x;
  if(g<ngroups){
    float s=0.f,q=0.f;
    for(int b=0;b<nblk;b++){ s+=part[(b*ngroups+g)*2+0]; q+=part[(b*ngroups+g)*2+1]; }
    float m = s*invN;
    float v = q*invN - m*m;
    stats[g*2+0]=m;
    stats[g*2+1]=rsqrtf(v+1e-5f);
  }
}

// ---------------- weight transpose+convert: out[n][k] = bf16(in[k][n]) ----------------
__global__ __launch_bounds__(256) void wcvt_k(const float* __restrict__ in,
                                              __bf16* __restrict__ out, int K, int N){
  int idx = blockIdx.x*256 + threadIdx.x;
  if(idx < N*K){
    int n = idx / K, k = idx - n*K;
    out[idx] = (__bf16)in[(size_t)k*N + n];
  }
}

__global__ __launch_bounds__(256) void zfill_bf16(__bf16* __restrict__ p, int n){
  int i = blockIdx.x*256 + threadIdx.x;
  if(i<n) p[i] = (__bf16)0.f;
}

// ---------------- MFMA bf16 GEMM ----------------
// C[M,N] = act( prolog(A)[M,K] @ B[K,N] + bias ).  B TRANSPOSED bf16 [N][K].
// 128x128 tile, BK=32, 4 waves (2x2), 4x4 16x16x32 tiles per wave.
// If VB != nullptr (u2 GEMM): cols<512 go to bf16 vbf[h][m][j][c] instead of fp32 C.
template<int AMODE, int ACT, int CBF16>
__global__ __launch_bounds__(256) void gemm_mfma(const void* __restrict__ Aip,
                                                 const __bf16* __restrict__ Bt,
                                                 const float* __restrict__ bias,
                                                 void* __restrict__ Cp,
                                                 int M, int N, int K,
                                                 const float* __restrict__ gstats,
                                                 const float* __restrict__ gw,
                                                 const float* __restrict__ gb,
                                                 int gshift,
                                                 __bf16* __restrict__ VB)
{
  __shared__ __bf16 As[128][40];
  __shared__ __bf16 Bs[128][40];
  const int tid  = threadIdx.x;
  const int row0 = blockIdx.y*128, col0 = blockIdx.x*128;
  const int r = tid & 127, h = tid >> 7;
  const int lane = tid & 63, wave = tid >> 6;
  const int wr = (wave >> 1)*64, wc = (wave & 1)*64;
  const int m16 = lane & 15, quad = lane >> 4;

  floatx4 acc[4][4];
  #pragma unroll
  for(int i=0;i<4;i++)
    #pragma unroll
    for(int j=0;j<4;j++) acc[i][j] = (floatx4)0.f;

  const int agr = row0 + r;
  for(int k0=0; k0<K; k0+=32){
    {
      __bf16 av[16];
      if(agr < M){
        if(AMODE==0){
          const __bf16* ap = (const __bf16*)Aip + (size_t)agr*K + k0 + h*16;
          bf16x8 v0 = *(const bf16x8*)ap;
          bf16x8 v1 = *(const bf16x8*)(ap+8);
          #pragma unroll
          for(int l=0;l<8;l++){ av[l]=v0[l]; av[8+l]=v1[l]; }
        } else {
          const float* ap = (const float*)Aip + (size_t)agr*K + k0 + h*16;
          #pragma unroll
          for(int l=0;l<16;l++){
            int c = k0 + h*16 + l;
            int g = c >> gshift;
            float v = (ap[l] - gstats[g*2+0]) * gstats[g*2+1] * gw[c] + gb[c];
            av[l] = (__bf16)v;
          }
        }
      } else {
        #pragma unroll
        for(int l=0;l<16;l++) av[l] = (__bf16)0.f;
      }
      bf16x8 w0, w1;
      #pragma unroll
      for(int l=0;l<8;l++){ w0[l]=av[l]; w1[l]=av[8+l]; }
      *(bf16x8*)&As[r][h*16]     = w0;
      *(bf16x8*)&As[r][h*16 + 8] = w1;
    }
    {
      const __bf16* bp = Bt + (size_t)(col0 + r)*K + k0 + h*16;
      *(bf16x8*)&Bs[r][h*16]     = *(const bf16x8*)bp;
      *(bf16x8*)&Bs[r][h*16 + 8] = *(const bf16x8*)(bp+8);
    }
    __syncthreads();

    bf16x8 af[4], bfv[4];
    #pragma unroll
    for(int ti=0;ti<4;ti++) af[ti]  = *(const bf16x8*)&As[wr + ti*16 + m16][quad*8];
    #pragma unroll
    for(int tj=0;tj<4;tj++) bfv[tj] = *(const bf16x8*)&Bs[wc + tj*16 + m16][quad*8];
    #pragma unroll
    for(int ti=0;ti<4;ti++)
      #pragma unroll
      for(int tj=0;tj<4;tj++)
        acc[ti][tj] = __builtin_amdgcn_mfma_f32_16x16x32_bf16(af[ti], bfv[tj], acc[ti][tj], 0,0,0);
    __syncthreads();
  }

  #pragma unroll
  for(int ti=0;ti<4;ti++){
    #pragma unroll
    for(int reg=0;reg<4;reg++){
      int gr = row0 + wr + ti*16 + quad*4 + reg;
      if(gr >= M) continue;
      int jj = gr/180, mm = gr - jj*180;   // only used for VB path
      #pragma unroll
      for(int tj=0;tj<4;tj++){
        int gc = col0 + wc + tj*16 + m16;
        float v = acc[ti][tj][reg];
        if(bias) v += bias[gc];
        if(ACT==1) v = gelu_tanh(v);
        if(VB && gc < 512){
          int hh = gc>>6, cc = gc&63;
          VB[(((size_t)(hh*180+mm)*91)+jj)*64 + cc] = (__bf16)v;
        } else if(CBF16){
          ((__bf16*)Cp)[(size_t)gr*N + gc] = (__bf16)v;
        } else {
          ((float*)Cp)[(size_t)gr*N + gc]  = v;
        }
      }
    }
  }
}

// ---------------- latitude weights ----------------
__global__ __launch_bounds__(128) void wlat_k(const float* __restrict__ lat,
                                              float* __restrict__ w, int n){
  int i = threadIdx.x;
  if(i<n) w[i] = cosf(lat[i]);
  __syncthreads();
  if(i==0){
    float dlat = lat[1]-lat[0];
    float s4 = sinf(dlat*0.25f);
    float pw = s4*s4 / sinf(dlat*0.5f);
    if(w[0]   < 0.001f) w[0]   = pw;
    if(w[n-1] < 0.001f) w[n-1] = pw;
  }
}

// ---------------- means over lat / lon of u_mid (u2 channels 512..767) ----------------
__global__ __launch_bounds__(256) void mean_over_lat(const float* __restrict__ u2,
                                                     float* __restrict__ out){
  int lon = blockIdx.x, c = threadIdx.x;
  float s=0.f;
  for(int j=0;j<91;j++) s += u2[((size_t)(j*180+lon))*768 + 512 + c];
  out[lon*256+c] = s*(1.0f/91.0f);
}
__global__ __launch_bounds__(256) void mean_over_lon(const float* __restrict__ u2,
                                                     float* __restrict__ out){
  int latr = blockIdx.x, c = threadIdx.x;
  const float* base = u2 + (size_t)(latr*180)*768 + 512 + c;
  float s=0.f;
  for(int m=0;m<180;m++) s += base[(size_t)m*768];
  out[latr*256+c] = s*(1.0f/180.0f);
}

// ---------------- fused pooling reducer: (mean@in_w)[, *rs] -> LN -> gated MLP ----------------
__global__ __launch_bounds__(256) void fused_pool_mlp(
    const float* __restrict__ x,    // [R][256] mean
    const float* __restrict__ rs,   // optional per-row scale (wlat) or nullptr
    const float* __restrict__ inw,  // [256][256]
    const float* __restrict__ lnw, const float* __restrict__ lnb,
    const float* __restrict__ w1, const float* __restrict__ b1,  // [256][512]
    const float* __restrict__ w2, const float* __restrict__ b2,  // [256][256]
    float* __restrict__ out){       // [R][256]
  int r = blockIdx.x, t = threadIdx.x;
  __shared__ float xs[256], xn[256], red[256], g[256];
  xs[t] = x[r*256+t];
  __syncthreads();
  float y=0.f;
  for(int c=0;c<256;c++) y += xs[c]*inw[c*256+t];
  if(rs) y *= rs[r];
  red[t]=y; __syncthreads();
  for(int s=128;s>0;s>>=1){ if(t<s) red[t]+=red[t+s]; __syncthreads(); }
  float m = red[0]*(1.f/256.f); __syncthreads();
  float d = y-m; red[t]=d*d; __syncthreads();
  for(int s=128;s>0;s>>=1){ if(t<s) red[t]+=red[t+s]; __syncthreads(); }
  float var = red[0]*(1.f/256.f);
  __syncthreads();
  xn[t] = d*rsqrtf(var+1e-5f)*lnw[t]+lnb[t];
  __syncthreads();
  float s1=b1[t], s2=b1[256+t];
  for(int c=0;c<256;c++){ float xv=xn[c]; s1 += xv*w1[c*512+t]; s2 += xv*w1[c*512+256+t]; }
  g[t] = gelu_tanh(s1)*s2;
  __syncthreads();
  float o=b2[t];
  for(int c=0;c<256;c++) o += g[c]*w2[c*256+t];
  out[r*256+t]=o;
}

// ---------------- small row GEMM (k-projections) ----------------
__global__ __launch_bounds__(256) void rowmm_k(const float* __restrict__ X,
                                               const float* __restrict__ W,
                                               const float* __restrict__ bias,
                                               float* __restrict__ out, int N){
  int r = blockIdx.x;
  int j = blockIdx.y*256 + threadIdx.x;
  __shared__ float xs[256];
  xs[threadIdx.x] = X[r*256 + threadIdx.x];
  __syncthreads();
  float s = bias ? bias[j] : 0.f;
  for(int c=0;c<256;c++) s += xs[c]*W[(size_t)c*N+j];
  out[(size_t)r*N+j]=s;
}

// ---------------- modulation table ----------------
__global__ __launch_bounds__(256) void modu_k(const float* __restrict__ coord,
                                              const float* __restrict__ freqs,
                                              const float* __restrict__ W,
                                              float* __restrict__ out,
                                              int nm, int nk, int periodic){
  int h = blockIdx.x / nm, m = blockIdx.x % nm;
  __shared__ float basis[64];
  int t = threadIdx.x;
  float dist = fabsf(coord[m] - coord[0]);
  if(periodic && dist > PI_F) dist = 2.f*PI_F - dist;
  float d = dist + 1e-5f;
  if(t < nk) basis[t] = 0.7978845608028654f * sinf(freqs[t]*d/PI_F) / d;
  __syncthreads();
  if(t < 192){
    float s=0.f;
    for(int k=0;k<nk;k++) s += basis[k]*W[(size_t)(k*8+h)*192+t];
    out[(size_t)(h*nm+m)*192+t]=s;
  }
}

// ---------------- low-rank kernel -> zero-padded bf16 [h][PITCH][PITCH] ----------------
__global__ __launch_bounds__(256) void lrk_k(const float* __restrict__ qry,
                                             const float* __restrict__ klk,
                                             const float* __restrict__ modu,
                                             const float* __restrict__ jscale,
                                             __bf16* __restrict__ out,
                                             int n, int pitch, float scale){
  int h = blockIdx.x / n, i = blockIdx.x % n;
  __shared__ float qs[192];
  int t=threadIdx.x;
  if(t<192) qs[t] = qry[(size_t)i*1536 + h*192 + t];
  __syncthreads();
  int j = t;
  if(j < n){
    int m = abs(i-j);
    const float* kp = &klk[(size_t)j*1536 + h*192];
    const float* mp = &modu[(size_t)(h*n + m)*192];
    float s=0.f;
    #pragma unroll 4
    for(int d=0;d<192;d++) s += qs[d]*kp[d]*mp[d];
    s = (s>=0.f) ? s : 0.2f*s;
    if(jscale) s *= jscale[j];
    out[((size_t)h*pitch + i)*pitch + j] = (__bf16)(s*scale);
  }
}

// ---------------- apply1 MFMA: per (h,m): C[91,64] = klat[h](91x91) @ V(91x64) ----------------
// Kl: bf16 [8][96][96] (j zero-padded). vbf: bf16 [8][180][91][64]. u1: bf16 [8][91][180][64].
__global__ __launch_bounds__(256) void apply1_mfma(const __bf16* __restrict__ Kl,
                                                   const __bf16* __restrict__ vbf,
                                                   __bf16* __restrict__ u1){
  int h = blockIdx.x / 180, m = blockIdx.x % 180;
  __shared__ __bf16 vst[64][104];           // [c][j], 104 keeps rows 16B-aligned
  int t = threadIdx.x;
  const __bf16* src = vbf + ((size_t)(h*180+m)*91)*64;
  for(int idx=t; idx<91*64; idx+=256){
    int j = idx>>6, c = idx&63;
    vst[c][j] = src[idx];
  }
  for(int idx=t; idx<64*13; idx+=256){      // zero pads j=91..103
    int c = idx/13, j = 91 + idx - (idx/13)*13;
    vst[c][j] = (__bf16)0.f;
  }
  __syncthreads();
  int lane = t & 63, wave = t>>6;
  int m16 = lane & 15, quad = lane>>4;
  floatx4 acc[6];
  #pragma unroll
  for(int i=0;i<6;i++) acc[i]=(floatx4)0.f;
  const __bf16* Ab = Kl + (size_t)h*96*96;
  #pragma unroll
  for(int kc=0; kc<3; kc++){
    bf16x8 bfrag = *(const bf16x8*)&vst[wave*16 + m16][kc*32 + quad*8];
    #pragma unroll
    for(int ti=0;ti<6;ti++){
      bf16x8 afrag = *(const bf16x8*)&Ab[(size_t)(ti*16+m16)*96 + kc*32 + quad*8];
      acc[ti] = __builtin_amdgcn_mfma_f32_16x16x32_bf16(afrag, bfrag, acc[ti], 0,0,0);
    }
  }
  #pragma unroll
  for(int ti=0;ti<6;ti++){
    #pragma unroll
    for(int reg=0;reg<4;reg++){
      int i = ti*16 + quad*4 + reg;
      if(i<91){
        int c = wave*16 + m16;
        u1[(((size_t)(h*91+i)*180)+m)*64 + c] = (__bf16)acc[ti][reg];
      }
    }
  }
}

// ---------------- apply2 MFMA: per (h,i): C[180,64] = klong[h](180x180) @ u1[h,i](180x64) ----------------
// Kg: bf16 [8][192][192] (m zero-padded). uphi fp32 [91][180][512].
__global__ __launch_bounds__(256) void apply2_mfma(const __bf16* __restrict__ Kg,
                                                   const __bf16* __restrict__ u1,
                                                   float* __restrict__ uphi){
  int h = blockIdx.x / 91, i = blockIdx.x % 91;
  __shared__ __bf16 vst[64][208];           // [c][m]
  int t = threadIdx.x;
  const __bf16* src = u1 + ((size_t)(h*91+i)*180)*64;
  for(int idx=t; idx<180*64; idx+=256){
    int m = idx>>6, c = idx&63;
    vst[c][m] = src[idx];
  }
  for(int idx=t; idx<64*28; idx+=256){      // zero pads m=180..207
    int c = idx/28, m = 180 + idx - (idx/28)*28;
    vst[c][m] = (__bf16)0.f;
  }
  __syncthreads();
  int lane = t&63, wave = t>>6;
  int m16 = lane&15, quad = lane>>4;
  floatx4 acc[12];
  #pragma unroll
  for(int l=0;l<12;l++) acc[l]=(floatx4)0.f;
  const __bf16* Ab = Kg + (size_t)h*192*192;
  for(int kc=0; kc<6; kc++){
    bf16x8 bfrag = *(const bf16x8*)&vst[wave*16+m16][kc*32 + quad*8];
    #pragma unroll
    for(int tl=0; tl<12; tl++){
      bf16x8 afrag = *(const bf16x8*)&Ab[(size_t)(tl*16+m16)*192 + kc*32 + quad*8];
      acc[tl] = __builtin_amdgcn_mfma_f32_16x16x32_bf16(afrag, bfrag, acc[tl], 0,0,0);
    }
  }
  #pragma unroll
  for(int tl=0; tl<12; tl++){
    #pragma unroll
    for(int reg=0; reg<4; reg++){
      int l = tl*16 + quad*4 + reg;
      if(l<180){
        int c = wave*16+m16;
        uphi[((size_t)i*180 + l)*512 + h*64 + c] = acc[tl][reg];
      }
    }
  }
}

// ---------------------------------------------------------------------------
extern "C" void kernel_launch(void* const* d_in, const int* in_sizes, int n_in,
                              void* d_out, int out_size, void* d_ws, size_t ws_size,
                              hipStream_t stream){
  const float* u_src      = (const float*)d_in[0];
  const float* u_lat_qry  = (const float*)d_in[1];
  const float* u_long_qry = (const float*)d_in[2];
  const float* lat = (const float*)d_in[3];
  const float* lon = (const float*)((in_sizes[4]==180)? d_in[4] : d_in[5]);
  const float* cm_gn_w = (const float*)d_in[7];
  const float* cm_gn_b = (const float*)d_in[8];
  const float* cm_w1   = (const float*)d_in[9];
  const float* cm_b1   = (const float*)d_in[10];
  const float* cm_w2   = (const float*)d_in[11];
  const float* cm_b2   = (const float*)d_in[12];
  const float* tl_in_w = (const float*)d_in[13];
  const float* tl_ln_w = (const float*)d_in[14];
  const float* tl_ln_b = (const float*)d_in[15];
  const float* tl_w1   = (const float*)d_in[16];
  const float* tl_b1   = (const float*)d_in[17];
  const float* tl_w2   = (const float*)d_in[18];
  const float* tl_b2   = (const float*)d_in[19];
  const float* ta_in_w = (const float*)d_in[20];
  const float* ta_ln_w = (const float*)d_in[21];
  const float* ta_ln_b = (const float*)d_in[22];
  const float* ta_w1   = (const float*)d_in[23];
  const float* ta_b1   = (const float*)d_in[24];
  const float* ta_w2   = (const float*)d_in[25];
  const float* ta_b2   = (const float*)d_in[26];
  const float* klong_wk= (const float*)d_in[27];
  const float* klat_wk = (const float*)d_in[28];
  const float* pe_long_freq = (const float*)d_in[29];
  const float* pe_long_w    = (const float*)d_in[30];
  const float* pe_lat_freq  = (const float*)d_in[31];
  const float* pe_lat_w     = (const float*)d_in[32];
  const float* mh_gn_w = (const float*)d_in[33];
  const float* mh_gn_b = (const float*)d_in[34];
  const float* mh_w    = (const float*)d_in[35];

  float* ws = (float*)d_ws;
  // ---- workspace layout (float offsets). Peak ~108 MB (ws >= 126 MB verified R1). ----
  const size_t OFF_PART1  = 0;          // 15360
  const size_t OFF_GN1    = 16384;      // 64
  const size_t OFF_WLAT   = 16512;      // 91
  const size_t OFF_MEANLAT= 16640;      // 46080
  const size_t OFF_MEANLON= 62720;      // 23296
  const size_t OFF_ULSRC  = 155392;     // 46080
  const size_t OFF_UASRC  = 201472;     // 23296
  const size_t OFF_KLKL   = 224768;     // 276480 fp32 kproj long [180][1536]
  const size_t OFF_KLKA   = 501248;     // 139776 fp32 kproj lat  [91][1536]
  const size_t OFF_MODUL  = 641024;     // 276480
  const size_t OFF_MODUA  = 917504;     // 139776
  const size_t OFF_KBL    = 1057280;    // bf16 8*96*96   -> 36864 f (adjacent to KBG)
  const size_t OFF_KBG    = 1094144;    // bf16 8*192*192 -> 147456 f
  const size_t OFF_PART2  = 1241600;    // 3840
  const size_t OFF_GN2    = 1245440;    // 16
  const size_t OFF_WT1    = 1245456;    // bf16 cm_w1^T -> 131072 f
  const size_t OFF_WT2    = 1376528;    // bf16 cm_w2^T -> 393216 f
  const size_t OFF_WT3    = 1769744;    // bf16 mh_w^T  -> 65536 f
  const size_t OFF_VBF    = 1835280;    // bf16 [8][180][91][64] -> 4193280 f
  const size_t OFF_U2     = 6028560;    // fp32 16380x768 -> 12579840 f (uphi reuses)
  const size_t OFF_UPHI   = 6028560;    // fp32 16380x512 (after means read u2)
  const size_t OFF_H1     = 18608400;   // bf16 16380x1024 -> 8386560 f
  const size_t OFF_U1     = 18608400;   // bf16 [8][91][180][64] (reuses H1, dead post-u2)

  const int NPOS = 16380;

  // 0) weight cvt + zero-fill padded K buffers
  wcvt_k<<<(256*1024+255)/256,256,0,stream>>>(cm_w1, (__bf16*)(ws+OFF_WT1), 256, 1024);
  wcvt_k<<<(1024*768+255)/256,256,0,stream>>>(cm_w2, (__bf16*)(ws+OFF_WT2), 1024, 768);
  wcvt_k<<<(512*256+255)/256,256,0,stream>>>(mh_w,  (__bf16*)(ws+OFF_WT3), 512, 256);
  zfill_bf16<<<(368640+255)/256,256,0,stream>>>((__bf16*)(ws+OFF_KBL), 368640);

  // 1) GN1 stats
  gn1_partial<<<240,256,0,stream>>>(u_src, ws+OFF_PART1, NPOS);
  gn_final<<<1,64,0,stream>>>(ws+OFF_PART1, ws+OFF_GN1, 240, 32, 1.f/131040.f);

  // 2) h1 = gelu(GN(u_src) @ cm_w1 + cm_b1)  [16380 x 1024] bf16
  gemm_mfma<1,1,1><<<dim3(8,128),256,0,stream>>>(u_src, (__bf16*)(ws+OFF_WT1), cm_b1,
      ws+OFF_H1, NPOS, 1024, 256, ws+OFF_GN1, cm_gn_w, cm_gn_b, 3, nullptr);

  // 3) u2 = h1 @ cm_w2 + cm_b2: cols<512 -> bf16 vbf[h][m][j][c]; cols>=512 -> fp32 u2
  gemm_mfma<0,0,0><<<dim3(6,128),256,0,stream>>>(ws+OFF_H1, (__bf16*)(ws+OFF_WT2), cm_b2,
      ws+OFF_U2, NPOS, 768, 1024, nullptr, nullptr, nullptr, 0, (__bf16*)(ws+OFF_VBF));

  // 4) latitude weights
  wlat_k<<<1,128,0,stream>>>(lat, ws+OFF_WLAT, 91);

  // 5) pooling means (u_mid channels)
  mean_over_lat<<<180,256,0,stream>>>(ws+OFF_U2, ws+OFF_MEANLAT);
  mean_over_lon<<<91,256,0,stream>>>(ws+OFF_U2, ws+OFF_MEANLON);

  // 6+7) fused: (mean@in_w)[*wlat] -> LN -> gated MLP
  fused_pool_mlp<<<180,256,0,stream>>>(ws+OFF_MEANLAT, nullptr,     tl_in_w, tl_ln_w, tl_ln_b,
      tl_w1, tl_b1, tl_w2, tl_b2, ws+OFF_ULSRC);
  fused_pool_mlp<<<91,256,0,stream>>>(ws+OFF_MEANLON, ws+OFF_WLAT, ta_in_w, ta_ln_w, ta_ln_b,
      ta_w1, ta_b1, ta_w2, ta_b2, ws+OFF_UASRC);

  // 8) k-projections
  rowmm_k<<<dim3(180,6),256,0,stream>>>(ws+OFF_ULSRC, klong_wk, nullptr, ws+OFF_KLKL, 1536);
  rowmm_k<<<dim3(91,6), 256,0,stream>>>(ws+OFF_UASRC, klat_wk, nullptr, ws+OFF_KLKA, 1536);

  // 9) modulation tables (|i-j| distinct distances only)
  modu_k<<<8*180,192,0,stream>>>(lon, pe_long_freq, pe_long_w, ws+OFF_MODUL, 180, 64, 1);
  modu_k<<<8*91, 192,0,stream>>>(lat, pe_lat_freq,  pe_lat_w,  ws+OFF_MODUA, 91, 32, 0);

  // 10) low-rank kernels -> padded bf16 (leaky + quadrature + wlat folded)
  lrk_k<<<8*180,256,0,stream>>>(u_long_qry, ws+OFF_KLKL, ws+OFF_MODUL, nullptr,
      (__bf16*)(ws+OFF_KBG), 180, 192, 2.f*PI_F/180.f);
  lrk_k<<<8*91, 256,0,stream>>>(u_lat_qry,  ws+OFF_KLKA, ws+OFF_MODUA, ws+OFF_WLAT,
      (__bf16*)(ws+OFF_KBL), 91, 96, PI_F/91.f);

  // 11) kernel application (MFMA)
  apply1_mfma<<<8*180,256,0,stream>>>((const __bf16*)(ws+OFF_KBL), (const __bf16*)(ws+OFF_VBF),
      (__bf16*)(ws+OFF_U1));
  apply2_mfma<<<8*91, 256,0,stream>>>((const __bf16*)(ws+OFF_KBG), (const __bf16*)(ws+OFF_U1),
      ws+OFF_UPHI);

  // 12) GN2 + final projection
  gn2_partial<<<240,256,0,stream>>>(ws+OFF_UPHI, ws+OFF_PART2, NPOS);
  gn_final<<<1,64,0,stream>>>(ws+OFF_PART2, ws+OFF_GN2, 240, 8, 1.f/1048320.f);
  gemm_mfma<1,0,0><<<dim3(2,128),256,0,stream>>>(ws+OFF_UPHI, (__bf16*)(ws+OFF_WT3), nullptr,
      (float*)d_out, NPOS, 256, 512, ws+OFF_GN2, mh_gn_w, mh_gn_b, 6, nullptr);
}

// Round 4
// 727.808 us; speedup vs baseline: 2.5319x; 1.1158x over previous
//
#include <hip/hip_runtime.h>
#include <math.h>

#define PI_F 3.14159265358979323846f

typedef __bf16  bf16x8  __attribute__((ext_vector_type(8)));
typedef float   floatx4 __attribute__((ext_vector_type(4)));

__device__ __forceinline__ float gelu_tanh(float x){
  float x3 = x*x*x;
  float t = tanhf(0.7978845608028654f*(x + 0.044715f*x3));
  return 0.5f*x*(1.0f+t);
}

// ---------------- group norm stats (deterministic two-pass) ----------------
__global__ __launch_bounds__(256) void gn1_partial(const float* __restrict__ x,
                                                   float* __restrict__ part, int npos){
  int c = threadIdx.x;
  float s=0.f, q=0.f;
  for(int p=blockIdx.x; p<npos; p+=gridDim.x){
    float v = x[p*256 + c];
    s += v; q += v*v;
  }
  __shared__ float ss[256], sq[256];
  ss[c]=s; sq[c]=q;
  __syncthreads();
  if((c&7)==0){
    float a=0.f,b=0.f;
    #pragma unroll
    for(int k=0;k<8;k++){ a+=ss[c+k]; b+=sq[c+k]; }
    int g=c>>3;
    part[(blockIdx.x*32+g)*2+0]=a;
    part[(blockIdx.x*32+g)*2+1]=b;
  }
}

__global__ __launch_bounds__(256) void gn2_partial(const float* __restrict__ x,
                                                   float* __restrict__ part, int npos){
  int t=threadIdx.x;
  float s0=0.f,q0=0.f,s1=0.f,q1=0.f;
  for(int p=blockIdx.x;p<npos;p+=gridDim.x){
    float v0=x[p*512+t];
    float v1=x[p*512+256+t];
    s0+=v0;q0+=v0*v0;s1+=v1;q1+=v1*v1;
  }
  __shared__ float ss[512], sq[512];
  ss[t]=s0; sq[t]=q0; ss[t+256]=s1; sq[t+256]=q1;
  __syncthreads();
  if(t<8){
    float a=0.f,b=0.f;
    for(int k=0;k<64;k++){ a+=ss[t*64+k]; b+=sq[t*64+k]; }
    part[(blockIdx.x*8+t)*2+0]=a;
    part[(blockIdx.x*8+t)*2+1]=b;
  }
}

__global__ __launch_bounds__(64) void gn_final(const float* __restrict__ part,
                                               float* __restrict__ stats,
                                               int nblk, int ngroups, float invN){
  int g = threadIdx.x;
  if(g<ngroups){
    float s=0.f,q=0.f;
    for(int b=0;b<nblk;b++){ s+=part[(b*ngroups+g)*2+0]; q+=part[(b*ngroups+g)*2+1]; }
    float m = s*invN;
    float v = q*invN - m*m;
    stats[g*2+0]=m;
    stats[g*2+1]=rsqrtf(v+1e-5f);
  }
}

// ---------------- weight transpose+convert: out[n][k] = bf16(in[k][n]) ----------------
__global__ __launch_bounds__(256) void wcvt_k(const float* __restrict__ in,
                                              __bf16* __restrict__ out, int K, int N){
  int idx = blockIdx.x*256 + threadIdx.x;
  if(idx < N*K){
    int n = idx / K, k = idx - n*K;
    out[idx] = (__bf16)in[(size_t)k*N + n];
  }
}

__global__ __launch_bounds__(256) void zfill_bf16(__bf16* __restrict__ p, int n){
  int i = blockIdx.x*256 + threadIdx.x;
  if(i<n) p[i] = (__bf16)0.f;
}

// ---------------- MFMA bf16 GEMM ----------------
// C[M,N] = act( prolog(A)[M,K] @ B[K,N] + bias ).  B TRANSPOSED bf16 [N][K].
// 128x128 tile, BK=32, 4 waves (2x2), 4x4 16x16x32 tiles per wave.
// If VB != nullptr (u2 GEMM): cols<512 go to bf16 vbf[h][m][j][c] instead of fp32 C.
template<int AMODE, int ACT, int CBF16>
__global__ __launch_bounds__(256) void gemm_mfma(const void* __restrict__ Aip,
                                                 const __bf16* __restrict__ Bt,
                                                 const float* __restrict__ bias,
                                                 void* __restrict__ Cp,
                                                 int M, int N, int K,
                                                 const float* __restrict__ gstats,
                                                 const float* __restrict__ gw,
                                                 const float* __restrict__ gb,
                                                 int gshift,
                                                 __bf16* __restrict__ VB)
{
  __shared__ __bf16 As[128][40];
  __shared__ __bf16 Bs[128][40];
  const int tid  = threadIdx.x;
  const int row0 = blockIdx.y*128, col0 = blockIdx.x*128;
  const int r = tid & 127, h = tid >> 7;
  const int lane = tid & 63, wave = tid >> 6;
  const int wr = (wave >> 1)*64, wc = (wave & 1)*64;
  const int m16 = lane & 15, quad = lane >> 4;

  floatx4 acc[4][4];
  #pragma unroll
  for(int i=0;i<4;i++)
    #pragma unroll
    for(int j=0;j<4;j++) acc[i][j] = (floatx4)0.f;

  const int agr = row0 + r;
  for(int k0=0; k0<K; k0+=32){
    {
      __bf16 av[16];
      if(agr < M){
        if(AMODE==0){
          const __bf16* ap = (const __bf16*)Aip + (size_t)agr*K + k0 + h*16;
          bf16x8 v0 = *(const bf16x8*)ap;
          bf16x8 v1 = *(const bf16x8*)(ap+8);
          #pragma unroll
          for(int l=0;l<8;l++){ av[l]=v0[l]; av[8+l]=v1[l]; }
        } else {
          const float* ap = (const float*)Aip + (size_t)agr*K + k0 + h*16;
          #pragma unroll
          for(int l=0;l<16;l++){
            int c = k0 + h*16 + l;
            int g = c >> gshift;
            float v = (ap[l] - gstats[g*2+0]) * gstats[g*2+1] * gw[c] + gb[c];
            av[l] = (__bf16)v;
          }
        }
      } else {
        #pragma unroll
        for(int l=0;l<16;l++) av[l] = (__bf16)0.f;
      }
      bf16x8 w0, w1;
      #pragma unroll
      for(int l=0;l<8;l++){ w0[l]=av[l]; w1[l]=av[8+l]; }
      *(bf16x8*)&As[r][h*16]     = w0;
      *(bf16x8*)&As[r][h*16 + 8] = w1;
    }
    {
      const __bf16* bp = Bt + (size_t)(col0 + r)*K + k0 + h*16;
      *(bf16x8*)&Bs[r][h*16]     = *(const bf16x8*)bp;
      *(bf16x8*)&Bs[r][h*16 + 8] = *(const bf16x8*)(bp+8);
    }
    __syncthreads();

    bf16x8 af[4], bfv[4];
    #pragma unroll
    for(int ti=0;ti<4;ti++) af[ti]  = *(const bf16x8*)&As[wr + ti*16 + m16][quad*8];
    #pragma unroll
    for(int tj=0;tj<4;tj++) bfv[tj] = *(const bf16x8*)&Bs[wc + tj*16 + m16][quad*8];
    #pragma unroll
    for(int ti=0;ti<4;ti++)
      #pragma unroll
      for(int tj=0;tj<4;tj++)
        acc[ti][tj] = __builtin_amdgcn_mfma_f32_16x16x32_bf16(af[ti], bfv[tj], acc[ti][tj], 0,0,0);
    __syncthreads();
  }

  #pragma unroll
  for(int ti=0;ti<4;ti++){
    #pragma unroll
    for(int reg=0;reg<4;reg++){
      int gr = row0 + wr + ti*16 + quad*4 + reg;
      if(gr >= M) continue;
      int jj = gr/180, mm = gr - jj*180;   // only used for VB path
      #pragma unroll
      for(int tj=0;tj<4;tj++){
        int gc = col0 + wc + tj*16 + m16;
        float v = acc[ti][tj][reg];
        if(bias) v += bias[gc];
        if(ACT==1) v = gelu_tanh(v);
        if(VB && gc < 512){
          int hh = gc>>6, cc = gc&63;
          VB[(((size_t)(hh*180+mm)*91)+jj)*64 + cc] = (__bf16)v;
        } else if(CBF16){
          ((__bf16*)Cp)[(size_t)gr*N + gc] = (__bf16)v;
        } else {
          ((float*)Cp)[(size_t)gr*N + gc]  = v;
        }
      }
    }
  }
}

// ---------------- latitude weights ----------------
__global__ __launch_bounds__(128) void wlat_k(const float* __restrict__ lat,
                                              float* __restrict__ w, int n){
  int i = threadIdx.x;
  if(i<n) w[i] = cosf(lat[i]);
  __syncthreads();
  if(i==0){
    float dlat = lat[1]-lat[0];
    float s4 = sinf(dlat*0.25f);
    float pw = s4*s4 / sinf(dlat*0.5f);
    if(w[0]   < 0.001f) w[0]   = pw;
    if(w[n-1] < 0.001f) w[n-1] = pw;
  }
}

// ---------------- means over lat / lon of u_mid (u2 channels 512..767) ----------------
__global__ __launch_bounds__(256) void mean_over_lat(const float* __restrict__ u2,
                                                     float* __restrict__ out){
  int lon = blockIdx.x, c = threadIdx.x;
  float s=0.f;
  for(int j=0;j<91;j++) s += u2[((size_t)(j*180+lon))*768 + 512 + c];
  out[lon*256+c] = s*(1.0f/91.0f);
}
__global__ __launch_bounds__(256) void mean_over_lon(const float* __restrict__ u2,
                                                     float* __restrict__ out){
  int latr = blockIdx.x, c = threadIdx.x;
  const float* base = u2 + (size_t)(latr*180)*768 + 512 + c;
  float s=0.f;
  for(int m=0;m<180;m++) s += base[(size_t)m*768];
  out[latr*256+c] = s*(1.0f/180.0f);
}

// ---------------- fused pooling reducer: (mean@in_w)[, *rs] -> LN -> gated MLP ----------------
__global__ __launch_bounds__(256) void fused_pool_mlp(
    const float* __restrict__ x,
    const float* __restrict__ rs,
    const float* __restrict__ inw,
    const float* __restrict__ lnw, const float* __restrict__ lnb,
    const float* __restrict__ w1, const float* __restrict__ b1,
    const float* __restrict__ w2, const float* __restrict__ b2,
    float* __restrict__ out){
  int r = blockIdx.x, t = threadIdx.x;
  __shared__ float xs[256], xn[256], red[256], g[256];
  xs[t] = x[r*256+t];
  __syncthreads();
  float y=0.f;
  for(int c=0;c<256;c++) y += xs[c]*inw[c*256+t];
  if(rs) y *= rs[r];
  red[t]=y; __syncthreads();
  for(int s=128;s>0;s>>=1){ if(t<s) red[t]+=red[t+s]; __syncthreads(); }
  float m = red[0]*(1.f/256.f); __syncthreads();
  float d = y-m; red[t]=d*d; __syncthreads();
  for(int s=128;s>0;s>>=1){ if(t<s) red[t]+=red[t+s]; __syncthreads(); }
  float var = red[0]*(1.f/256.f);
  __syncthreads();
  xn[t] = d*rsqrtf(var+1e-5f)*lnw[t]+lnb[t];
  __syncthreads();
  float s1=b1[t], s2=b1[256+t];
  for(int c=0;c<256;c++){ float xv=xn[c]; s1 += xv*w1[c*512+t]; s2 += xv*w1[c*512+256+t]; }
  g[t] = gelu_tanh(s1)*s2;
  __syncthreads();
  float o=b2[t];
  for(int c=0;c<256;c++) o += g[c]*w2[c*256+t];
  out[r*256+t]=o;
}

// ---------------- k-projection, TRANSPOSED output: out[col][r] ----------------
__global__ __launch_bounds__(256) void rowmm_kT(const float* __restrict__ X,
                                                const float* __restrict__ W,
                                                float* __restrict__ out,
                                                int N, int R){
  int r = blockIdx.x;
  int j = blockIdx.y*256 + threadIdx.x;
  __shared__ float xs[256];
  xs[threadIdx.x] = X[r*256 + threadIdx.x];
  __syncthreads();
  float s = 0.f;
  for(int c=0;c<256;c++) s += xs[c]*W[(size_t)c*N+j];
  out[(size_t)j*R + r] = s;
}

// ---------------- modulation table, TRANSPOSED: out[(h*192+d)][m] ----------------
__global__ __launch_bounds__(256) void modu_k(const float* __restrict__ coord,
                                              const float* __restrict__ freqs,
                                              const float* __restrict__ W,
                                              float* __restrict__ out,
                                              int nm, int nk, int periodic){
  int h = blockIdx.x / nm, m = blockIdx.x % nm;
  __shared__ float basis[64];
  int t = threadIdx.x;
  float dist = fabsf(coord[m] - coord[0]);
  if(periodic && dist > PI_F) dist = 2.f*PI_F - dist;
  float d = dist + 1e-5f;
  if(t < nk) basis[t] = 0.7978845608028654f * sinf(freqs[t]*d/PI_F) / d;
  __syncthreads();
  if(t < 192){
    float s=0.f;
    for(int k=0;k<nk;k++) s += basis[k]*W[(size_t)(k*8+h)*192+t];
    out[((size_t)h*192 + t)*nm + m] = s;
  }
}

// ---------------- low-rank kernel (coalesced): kt/mt are [h*192+d][n] ----------------
__global__ __launch_bounds__(256) void lrk_k(const float* __restrict__ qry,
                                             const float* __restrict__ kt,
                                             const float* __restrict__ mt,
                                             const float* __restrict__ jscale,
                                             __bf16* __restrict__ out,
                                             int n, int pitch, float scale){
  int h = blockIdx.x / n, i = blockIdx.x % n;
  __shared__ float qs[192];
  int t=threadIdx.x;
  if(t<192) qs[t] = qry[(size_t)i*1536 + h*192 + t];
  __syncthreads();
  int j = t;
  if(j < n){
    int m = abs(i-j);
    const float* kp = kt + (size_t)h*192*n;
    const float* mp = mt + (size_t)h*192*n;
    float s=0.f;
    #pragma unroll 4
    for(int d=0;d<192;d++) s += qs[d] * kp[(size_t)d*n + j] * mp[(size_t)d*n + m];
    s = (s>=0.f) ? s : 0.2f*s;
    if(jscale) s *= jscale[j];
    out[((size_t)h*pitch + i)*pitch + j] = (__bf16)(s*scale);
  }
}

// ---------------- apply1 MFMA: per (h,m): C[91,64] = klat[h](91x91) @ V(91x64) ----------------
__global__ __launch_bounds__(256) void apply1_mfma(const __bf16* __restrict__ Kl,
                                                   const __bf16* __restrict__ vbf,
                                                   __bf16* __restrict__ u1){
  int h = blockIdx.x / 180, m = blockIdx.x % 180;
  __shared__ __bf16 vst[64][104];
  int t = threadIdx.x;
  const __bf16* src = vbf + ((size_t)(h*180+m)*91)*64;
  for(int idx=t; idx<91*64; idx+=256){
    int j = idx>>6, c = idx&63;
    vst[c][j] = src[idx];
  }
  for(int idx=t; idx<64*13; idx+=256){
    int c = idx/13, j = 91 + idx - (idx/13)*13;
    vst[c][j] = (__bf16)0.f;
  }
  __syncthreads();
  int lane = t & 63, wave = t>>6;
  int m16 = lane & 15, quad = lane>>4;
  floatx4 acc[6];
  #pragma unroll
  for(int i=0;i<6;i++) acc[i]=(floatx4)0.f;
  const __bf16* Ab = Kl + (size_t)h*96*96;
  #pragma unroll
  for(int kc=0; kc<3; kc++){
    bf16x8 bfrag = *(const bf16x8*)&vst[wave*16 + m16][kc*32 + quad*8];
    #pragma unroll
    for(int ti=0;ti<6;ti++){
      bf16x8 afrag = *(const bf16x8*)&Ab[(size_t)(ti*16+m16)*96 + kc*32 + quad*8];
      acc[ti] = __builtin_amdgcn_mfma_f32_16x16x32_bf16(afrag, bfrag, acc[ti], 0,0,0);
    }
  }
  #pragma unroll
  for(int ti=0;ti<6;ti++){
    #pragma unroll
    for(int reg=0;reg<4;reg++){
      int i = ti*16 + quad*4 + reg;
      if(i<91){
        int c = wave*16 + m16;
        u1[(((size_t)(h*91+i)*180)+m)*64 + c] = (__bf16)acc[ti][reg];
      }
    }
  }
}

// ---------------- apply2 MFMA: per (h,i): C[180,64] = klong[h](180x180) @ u1[h,i](180x64) ----------------
__global__ __launch_bounds__(256) void apply2_mfma(const __bf16* __restrict__ Kg,
                                                   const __bf16* __restrict__ u1,
                                                   float* __restrict__ uphi){
  int h = blockIdx.x / 91, i = blockIdx.x % 91;
  __shared__ __bf16 vst[64][208];
  int t = threadIdx.x;
  const __bf16* src = u1 + ((size_t)(h*91+i)*180)*64;
  for(int idx=t; idx<180*64; idx+=256){
    int m = idx>>6, c = idx&63;
    vst[c][m] = src[idx];
  }
  for(int idx=t; idx<64*28; idx+=256){
    int c = idx/28, m = 180 + idx - (idx/28)*28;
    vst[c][m] = (__bf16)0.f;
  }
  __syncthreads();
  int lane = t&63, wave = t>>6;
  int m16 = lane&15, quad = lane>>4;
  floatx4 acc[12];
  #pragma unroll
  for(int l=0;l<12;l++) acc[l]=(floatx4)0.f;
  const __bf16* Ab = Kg + (size_t)h*192*192;
  for(int kc=0; kc<6; kc++){
    bf16x8 bfrag = *(const bf16x8*)&vst[wave*16+m16][kc*32 + quad*8];
    #pragma unroll
    for(int tl=0; tl<12; tl++){
      bf16x8 afrag = *(const bf16x8*)&Ab[(size_t)(tl*16+m16)*192 + kc*32 + quad*8];
      acc[tl] = __builtin_amdgcn_mfma_f32_16x16x32_bf16(afrag, bfrag, acc[tl], 0,0,0);
    }
  }
  #pragma unroll
  for(int tl=0; tl<12; tl++){
    #pragma unroll
    for(int reg=0; reg<4; reg++){
      int l = tl*16 + quad*4 + reg;
      if(l<180){
        int c = wave*16+m16;
        uphi[((size_t)i*180 + l)*512 + h*64 + c] = acc[tl][reg];
      }
    }
  }
}

// ---------------------------------------------------------------------------
extern "C" void kernel_launch(void* const* d_in, const int* in_sizes, int n_in,
                              void* d_out, int out_size, void* d_ws, size_t ws_size,
                              hipStream_t stream){
  const float* u_src      = (const float*)d_in[0];
  const float* u_lat_qry  = (const float*)d_in[1];
  const float* u_long_qry = (const float*)d_in[2];
  const float* lat = (const float*)d_in[3];
  const float* lon = (const float*)((in_sizes[4]==180)? d_in[4] : d_in[5]);
  const float* cm_gn_w = (const float*)d_in[7];
  const float* cm_gn_b = (const float*)d_in[8];
  const float* cm_w1   = (const float*)d_in[9];
  const float* cm_b1   = (const float*)d_in[10];
  const float* cm_w2   = (const float*)d_in[11];
  const float* cm_b2   = (const float*)d_in[12];
  const float* tl_in_w = (const float*)d_in[13];
  const float* tl_ln_w = (const float*)d_in[14];
  const float* tl_ln_b = (const float*)d_in[15];
  const float* tl_w1   = (const float*)d_in[16];
  const float* tl_b1   = (const float*)d_in[17];
  const float* tl_w2   = (const float*)d_in[18];
  const float* tl_b2   = (const float*)d_in[19];
  const float* ta_in_w = (const float*)d_in[20];
  const float* ta_ln_w = (const float*)d_in[21];
  const float* ta_ln_b = (const float*)d_in[22];
  const float* ta_w1   = (const float*)d_in[23];
  const float* ta_b1   = (const float*)d_in[24];
  const float* ta_w2   = (const float*)d_in[25];
  const float* ta_b2   = (const float*)d_in[26];
  const float* klong_wk= (const float*)d_in[27];
  const float* klat_wk = (const float*)d_in[28];
  const float* pe_long_freq = (const float*)d_in[29];
  const float* pe_long_w    = (const float*)d_in[30];
  const float* pe_lat_freq  = (const float*)d_in[31];
  const float* pe_lat_w     = (const float*)d_in[32];
  const float* mh_gn_w = (const float*)d_in[33];
  const float* mh_gn_b = (const float*)d_in[34];
  const float* mh_w    = (const float*)d_in[35];

  float* ws = (float*)d_ws;
  const size_t OFF_PART1  = 0;          // 15360
  const size_t OFF_GN1    = 16384;      // 64
  const size_t OFF_WLAT   = 16512;      // 91
  const size_t OFF_MEANLAT= 16640;      // 46080
  const size_t OFF_MEANLON= 62720;      // 23296
  const size_t OFF_ULSRC  = 155392;     // 46080
  const size_t OFF_UASRC  = 201472;     // 23296
  const size_t OFF_KLKL   = 224768;     // 276480 fp32 kprojT long [1536][180]
  const size_t OFF_KLKA   = 501248;     // 139776 fp32 kprojT lat  [1536][91]
  const size_t OFF_MODUL  = 641024;     // 276480 fp32 modT long [1536][180]
  const size_t OFF_MODUA  = 917504;     // 139776 fp32 modT lat  [1536][91]
  const size_t OFF_KBL    = 1057280;    // bf16 8*96*96   -> 36864 f
  const size_t OFF_KBG    = 1094144;    // bf16 8*192*192 -> 147456 f
  const size_t OFF_PART2  = 1241600;    // 3840
  const size_t OFF_GN2    = 1245440;    // 16
  const size_t OFF_WT1    = 1245456;    // bf16 cm_w1^T -> 131072 f
  const size_t OFF_WT2    = 1376528;    // bf16 cm_w2^T -> 393216 f
  const size_t OFF_WT3    = 1769744;    // bf16 mh_w^T  -> 65536 f
  const size_t OFF_VBF    = 1835280;    // bf16 [8][180][91][64] -> 4193280 f
  const size_t OFF_U2     = 6028560;    // fp32 16380x768
  const size_t OFF_UPHI   = 6028560;    // fp32 16380x512 (reuses u2)
  const size_t OFF_H1     = 18608400;   // bf16 16380x1024
  const size_t OFF_U1     = 18608400;   // bf16 (reuses H1)

  const int NPOS = 16380;

  // 0) weight cvt + zero-fill padded K buffers
  wcvt_k<<<(256*1024+255)/256,256,0,stream>>>(cm_w1, (__bf16*)(ws+OFF_WT1), 256, 1024);
  wcvt_k<<<(1024*768+255)/256,256,0,stream>>>(cm_w2, (__bf16*)(ws+OFF_WT2), 1024, 768);
  wcvt_k<<<(512*256+255)/256,256,0,stream>>>(mh_w,  (__bf16*)(ws+OFF_WT3), 512, 256);
  zfill_bf16<<<(368640+255)/256,256,0,stream>>>((__bf16*)(ws+OFF_KBL), 368640);

  // 1) GN1 stats
  gn1_partial<<<240,256,0,stream>>>(u_src, ws+OFF_PART1, NPOS);
  gn_final<<<1,64,0,stream>>>(ws+OFF_PART1, ws+OFF_GN1, 240, 32, 1.f/131040.f);

  // 2) h1 = gelu(GN(u_src) @ cm_w1 + cm_b1)  [16380 x 1024] bf16
  gemm_mfma<1,1,1><<<dim3(8,128),256,0,stream>>>(u_src, (__bf16*)(ws+OFF_WT1), cm_b1,
      ws+OFF_H1, NPOS, 1024, 256, ws+OFF_GN1, cm_gn_w, cm_gn_b, 3, nullptr);

  // 3) u2 = h1 @ cm_w2 + cm_b2: cols<512 -> bf16 vbf[h][m][j][c]; cols>=512 -> fp32 u2
  gemm_mfma<0,0,0><<<dim3(6,128),256,0,stream>>>(ws+OFF_H1, (__bf16*)(ws+OFF_WT2), cm_b2,
      ws+OFF_U2, NPOS, 768, 1024, nullptr, nullptr, nullptr, 0, (__bf16*)(ws+OFF_VBF));

  // 4) latitude weights
  wlat_k<<<1,128,0,stream>>>(lat, ws+OFF_WLAT, 91);

  // 5) pooling means (u_mid channels)
  mean_over_lat<<<180,256,0,stream>>>(ws+OFF_U2, ws+OFF_MEANLAT);
  mean_over_lon<<<91,256,0,stream>>>(ws+OFF_U2, ws+OFF_MEANLON);

  // 6+7) fused pooling MLPs
  fused_pool_mlp<<<180,256,0,stream>>>(ws+OFF_MEANLAT, nullptr,     tl_in_w, tl_ln_w, tl_ln_b,
      tl_w1, tl_b1, tl_w2, tl_b2, ws+OFF_ULSRC);
  fused_pool_mlp<<<91,256,0,stream>>>(ws+OFF_MEANLON, ws+OFF_WLAT, ta_in_w, ta_ln_w, ta_ln_b,
      ta_w1, ta_b1, ta_w2, ta_b2, ws+OFF_UASRC);

  // 8) k-projections -> transposed [1536][R] for coalesced lrk reads
  rowmm_kT<<<dim3(180,6),256,0,stream>>>(ws+OFF_ULSRC, klong_wk, ws+OFF_KLKL, 1536, 180);
  rowmm_kT<<<dim3(91,6), 256,0,stream>>>(ws+OFF_UASRC, klat_wk,  ws+OFF_KLKA, 1536, 91);

  // 9) modulation tables -> transposed [1536][nm]
  modu_k<<<8*180,192,0,stream>>>(lon, pe_long_freq, pe_long_w, ws+OFF_MODUL, 180, 64, 1);
  modu_k<<<8*91, 192,0,stream>>>(lat, pe_lat_freq,  pe_lat_w,  ws+OFF_MODUA, 91, 32, 0);

  // 10) low-rank kernels (coalesced d-major loads) -> padded bf16
  lrk_k<<<8*180,256,0,stream>>>(u_long_qry, ws+OFF_KLKL, ws+OFF_MODUL, nullptr,
      (__bf16*)(ws+OFF_KBG), 180, 192, 2.f*PI_F/180.f);
  lrk_k<<<8*91, 256,0,stream>>>(u_lat_qry,  ws+OFF_KLKA, ws+OFF_MODUA, ws+OFF_WLAT,
      (__bf16*)(ws+OFF_KBL), 91, 96, PI_F/91.f);

  // 11) kernel application (MFMA)
  apply1_mfma<<<8*180,256,0,stream>>>((const __bf16*)(ws+OFF_KBL), (const __bf16*)(ws+OFF_VBF),
      (__bf16*)(ws+OFF_U1));
  apply2_mfma<<<8*91, 256,0,stream>>>((const __bf16*)(ws+OFF_KBG), (const __bf16*)(ws+OFF_U1),
      ws+OFF_UPHI);

  // 12) GN2 + final projection
  gn2_partial<<<240,256,0,stream>>>(ws+OFF_UPHI, ws+OFF_PART2, NPOS);
  gn_final<<<1,64,0,stream>>>(ws+OFF_PART2, ws+OFF_GN2, 240, 8, 1.f/1048320.f);
  gemm_mfma<1,0,0><<<dim3(2,128),256,0,stream>>>(ws+OFF_UPHI, (__bf16*)(ws+OFF_WT3), nullptr,
      (float*)d_out, NPOS, 256, 512, ws+OFF_GN2, mh_gn_w, mh_gn_b, 6, nullptr);
}

// Round 5
// 617.071 us; speedup vs baseline: 2.9862x; 1.1795x over previous
//
#include <hip/hip_runtime.h>
#include <math.h>

#define PI_F 3.14159265358979323846f

typedef __bf16  bf16x8  __attribute__((ext_vector_type(8)));
typedef __bf16  bf16x4  __attribute__((ext_vector_type(4)));
typedef float   floatx4 __attribute__((ext_vector_type(4)));

__device__ __forceinline__ float gelu_tanh(float x){
  float x3 = x*x*x;
  float t = tanhf(0.7978845608028654f*(x + 0.044715f*x3));
  return 0.5f*x*(1.0f+t);
}

// async global->LDS 16B per lane; LDS dest = wave-uniform base + lane*16
__device__ __forceinline__ void gl_lds16(const void* g, void* l){
  __builtin_amdgcn_global_load_lds(
      (const __attribute__((address_space(1))) void*)(uintptr_t)g,
      (__attribute__((address_space(3))) void*)(uintptr_t)l,
      16, 0, 0);
}

// ---------------- group norm stats (deterministic two-pass) ----------------
__global__ __launch_bounds__(256) void gn1_partial(const float* __restrict__ x,
                                                   float* __restrict__ part, int npos){
  int c = threadIdx.x;
  float s=0.f, q=0.f;
  for(int p=blockIdx.x; p<npos; p+=gridDim.x){
    float v = x[p*256 + c];
    s += v; q += v*v;
  }
  __shared__ float ss[256], sq[256];
  ss[c]=s; sq[c]=q;
  __syncthreads();
  if((c&7)==0){
    float a=0.f,b=0.f;
    #pragma unroll
    for(int k=0;k<8;k++){ a+=ss[c+k]; b+=sq[c+k]; }
    int g=c>>3;
    part[(blockIdx.x*32+g)*2+0]=a;
    part[(blockIdx.x*32+g)*2+1]=b;
  }
}

__global__ __launch_bounds__(64) void gn_final(const float* __restrict__ part,
                                               float* __restrict__ stats,
                                               int nblk, int ngroups, float invN){
  int g = threadIdx.x;
  if(g<ngroups){
    float s=0.f,q=0.f;
    for(int b=0;b<nblk;b++){ s+=part[(b*ngroups+g)*2+0]; q+=part[(b*ngroups+g)*2+1]; }
    float m = s*invN;
    float v = q*invN - m*m;
    stats[g*2+0]=m;
    stats[g*2+1]=rsqrtf(v+1e-5f);
  }
}

// final reduce for GN2: part laid out [8][91] pairs
__global__ __launch_bounds__(64) void gn_final2(const float* __restrict__ part,
                                                float* __restrict__ stats, float invN){
  int g = threadIdx.x;
  if(g<8){
    float s=0.f,q=0.f;
    for(int i=0;i<91;i++){ s+=part[(g*91+i)*2+0]; q+=part[(g*91+i)*2+1]; }
    float m = s*invN;
    float v = q*invN - m*m;
    stats[g*2+0]=m;
    stats[g*2+1]=rsqrtf(v+1e-5f);
  }
}

// ---------------- GN-normalize + cast to bf16 (vectorized x4) ----------------
__global__ __launch_bounds__(256) void gncast_k(const float* __restrict__ x,
                                                const float* __restrict__ stats,
                                                const float* __restrict__ w,
                                                const float* __restrict__ b,
                                                __bf16* __restrict__ out,
                                                int total, int cmask, int gshift){
  int i4 = (blockIdx.x*256 + threadIdx.x)*4;
  if(i4 < total){
    float4 v = *(const float4*)(x+i4);
    int c0 = i4 & cmask;
    bf16x4 o;
    #pragma unroll
    for(int l=0;l<4;l++){
      int c = c0+l; int g = c>>gshift;
      float vv = (&v.x)[l];
      o[l] = (__bf16)((vv - stats[g*2+0])*stats[g*2+1]*w[c] + b[c]);
    }
    *(bf16x4*)(out+i4) = o;
  }
}

// ---------------- weight transpose+convert: out[n][k] = bf16(in[k][n]) ----------------
__global__ __launch_bounds__(256) void wcvt_k(const float* __restrict__ in,
                                              __bf16* __restrict__ out, int K, int N){
  int idx = blockIdx.x*256 + threadIdx.x;
  if(idx < N*K){
    int n = idx / K, k = idx - n*K;
    out[idx] = (__bf16)in[(size_t)k*N + n];
  }
}

__global__ __launch_bounds__(256) void zfill_bf16(__bf16* __restrict__ p, int n){
  int i = blockIdx.x*256 + threadIdx.x;
  if(i<n) p[i] = (__bf16)0.f;
}

// ---------------- MFMA bf16 GEMM with global_load_lds staging ----------------
// C[M,N] = act( A[M,K](bf16) @ B + bias ), B transposed bf16 [N][K].
// 128x128 tile, BK=32, 4 waves 2x2, 4x4 16x16x32 MFMA/wave. m97-style 2-barrier loop.
// OUTMODE: 0 = fp32 C, 1 = bf16 C, 2 = u2-split (cols<512 -> VB bf16 [h][m][j][c], rest fp32 C)
template<int ACT, int OUTMODE>
__global__ __launch_bounds__(256) void gemm_ld(const __bf16* __restrict__ A,
                                               const __bf16* __restrict__ Bt,
                                               const float* __restrict__ bias,
                                               void* __restrict__ Cp,
                                               __bf16* __restrict__ VB,
                                               int M, int N, int K)
{
  __shared__ __bf16 As[128][32];
  __shared__ __bf16 Bs[128][32];
  const int tid  = threadIdx.x;
  const int lane = tid & 63, wave = tid >> 6;
  const int row0 = blockIdx.y*128, col0 = blockIdx.x*128;
  const int lrow = lane >> 2;            // 16 rows per wave-load
  const int lcol = (lane & 3) * 8;       // 4 lanes x 16B cover one 64B row
  const int wr = (wave >> 1)*64, wc = (wave & 1)*64;
  const int m16 = lane & 15, quad = lane >> 4;

  const __bf16* Ag0 = A  + (size_t)(row0 + wave*32 + lrow)*K + lcol;
  const __bf16* Ag1 = Ag0 + (size_t)16*K;
  const __bf16* Bg0 = Bt + (size_t)(col0 + wave*32 + lrow)*K + lcol;
  const __bf16* Bg1 = Bg0 + (size_t)16*K;
  void* la0 = &As[wave*32     ][0];
  void* la1 = &As[wave*32 + 16][0];
  void* lb0 = &Bs[wave*32     ][0];
  void* lb1 = &Bs[wave*32 + 16][0];

  floatx4 acc[4][4];
  #pragma unroll
  for(int i=0;i<4;i++)
    #pragma unroll
    for(int j=0;j<4;j++) acc[i][j] = (floatx4)0.f;

  const int kiters = K >> 5;
  for(int kk=0; kk<kiters; kk++){
    __syncthreads();                       // prior iter's ds_reads done
    gl_lds16(Ag0, la0);
    gl_lds16(Ag1, la1);
    gl_lds16(Bg0, lb0);
    gl_lds16(Bg1, lb1);
    Ag0 += 32; Ag1 += 32; Bg0 += 32; Bg1 += 32;
    __syncthreads();                       // vmcnt drained -> LDS valid

    bf16x8 af[4], bfv[4];
    #pragma unroll
    for(int ti=0;ti<4;ti++) af[ti]  = *(const bf16x8*)&As[wr + ti*16 + m16][quad*8];
    #pragma unroll
    for(int tj=0;tj<4;tj++) bfv[tj] = *(const bf16x8*)&Bs[wc + tj*16 + m16][quad*8];
    #pragma unroll
    for(int ti=0;ti<4;ti++)
      #pragma unroll
      for(int tj=0;tj<4;tj++)
        acc[ti][tj] = __builtin_amdgcn_mfma_f32_16x16x32_bf16(af[ti], bfv[tj], acc[ti][tj], 0,0,0);
  }

  #pragma unroll
  for(int ti=0;ti<4;ti++){
    #pragma unroll
    for(int reg=0;reg<4;reg++){
      int gr = row0 + wr + ti*16 + quad*4 + reg;
      if(gr >= M) continue;
      int jj = gr/180, mm = gr - jj*180;   // only used for OUTMODE 2
      #pragma unroll
      for(int tj=0;tj<4;tj++){
        int gc = col0 + wc + tj*16 + m16;
        float v = acc[ti][tj][reg];
        if(bias) v += bias[gc];
        if(ACT==1) v = gelu_tanh(v);
        if(OUTMODE==2 && gc < 512){
          int hh = gc>>6, cc = gc&63;
          VB[(((size_t)(hh*180+mm)*91)+jj)*64 + cc] = (__bf16)v;
        } else if(OUTMODE==1){
          ((__bf16*)Cp)[(size_t)gr*N + gc] = (__bf16)v;
        } else {
          ((float*)Cp)[(size_t)gr*N + gc]  = v;
        }
      }
    }
  }
}

// ---------------- latitude weights ----------------
__global__ __launch_bounds__(128) void wlat_k(const float* __restrict__ lat,
                                              float* __restrict__ w, int n){
  int i = threadIdx.x;
  if(i<n) w[i] = cosf(lat[i]);
  __syncthreads();
  if(i==0){
    float dlat = lat[1]-lat[0];
    float s4 = sinf(dlat*0.25f);
    float pw = s4*s4 / sinf(dlat*0.5f);
    if(w[0]   < 0.001f) w[0]   = pw;
    if(w[n-1] < 0.001f) w[n-1] = pw;
  }
}

// ---------------- means over lat / lon of u_mid (u2 channels 512..767) ----------------
__global__ __launch_bounds__(256) void mean_over_lat(const float* __restrict__ u2,
                                                     float* __restrict__ out){
  int lon = blockIdx.x, c = threadIdx.x;
  float s=0.f;
  for(int j=0;j<91;j++) s += u2[((size_t)(j*180+lon))*768 + 512 + c];
  out[lon*256+c] = s*(1.0f/91.0f);
}
__global__ __launch_bounds__(256) void mean_over_lon(const float* __restrict__ u2,
                                                     float* __restrict__ out){
  int latr = blockIdx.x, c = threadIdx.x;
  const float* base = u2 + (size_t)(latr*180)*768 + 512 + c;
  float s=0.f;
  for(int m=0;m<180;m++) s += base[(size_t)m*768];
  out[latr*256+c] = s*(1.0f/180.0f);
}

// ---------------- fused pooling reducer ----------------
__global__ __launch_bounds__(256) void fused_pool_mlp(
    const float* __restrict__ x,
    const float* __restrict__ rs,
    const float* __restrict__ inw,
    const float* __restrict__ lnw, const float* __restrict__ lnb,
    const float* __restrict__ w1, const float* __restrict__ b1,
    const float* __restrict__ w2, const float* __restrict__ b2,
    float* __restrict__ out){
  int r = blockIdx.x, t = threadIdx.x;
  __shared__ float xs[256], xn[256], red[256], g[256];
  xs[t] = x[r*256+t];
  __syncthreads();
  float y=0.f;
  for(int c=0;c<256;c++) y += xs[c]*inw[c*256+t];
  if(rs) y *= rs[r];
  red[t]=y; __syncthreads();
  for(int s=128;s>0;s>>=1){ if(t<s) red[t]+=red[t+s]; __syncthreads(); }
  float m = red[0]*(1.f/256.f); __syncthreads();
  float d = y-m; red[t]=d*d; __syncthreads();
  for(int s=128;s>0;s>>=1){ if(t<s) red[t]+=red[t+s]; __syncthreads(); }
  float var = red[0]*(1.f/256.f);
  __syncthreads();
  xn[t] = d*rsqrtf(var+1e-5f)*lnw[t]+lnb[t];
  __syncthreads();
  float s1=b1[t], s2=b1[256+t];
  for(int c=0;c<256;c++){ float xv=xn[c]; s1 += xv*w1[c*512+t]; s2 += xv*w1[c*512+256+t]; }
  g[t] = gelu_tanh(s1)*s2;
  __syncthreads();
  float o=b2[t];
  for(int c=0;c<256;c++) o += g[c]*w2[c*256+t];
  out[r*256+t]=o;
}

// ---------------- k-projection, transposed output: out[col][r] ----------------
__global__ __launch_bounds__(256) void rowmm_kT(const float* __restrict__ X,
                                                const float* __restrict__ W,
                                                float* __restrict__ out,
                                                int N, int R){
  int r = blockIdx.x;
  int j = blockIdx.y*256 + threadIdx.x;
  __shared__ float xs[256];
  xs[threadIdx.x] = X[r*256 + threadIdx.x];
  __syncthreads();
  float s = 0.f;
  for(int c=0;c<256;c++) s += xs[c]*W[(size_t)c*N+j];
  out[(size_t)j*R + r] = s;
}

// ---------------- modulation table, transposed: out[(h*192+d)][m] ----------------
__global__ __launch_bounds__(256) void modu_k(const float* __restrict__ coord,
                                              const float* __restrict__ freqs,
                                              const float* __restrict__ W,
                                              float* __restrict__ out,
                                              int nm, int nk, int periodic){
  int h = blockIdx.x / nm, m = blockIdx.x % nm;
  __shared__ float basis[64];
  int t = threadIdx.x;
  float dist = fabsf(coord[m] - coord[0]);
  if(periodic && dist > PI_F) dist = 2.f*PI_F - dist;
  float d = dist + 1e-5f;
  if(t < nk) basis[t] = 0.7978845608028654f * sinf(freqs[t]*d/PI_F) / d;
  __syncthreads();
  if(t < 192){
    float s=0.f;
    for(int k=0;k<nk;k++) s += basis[k]*W[(size_t)(k*8+h)*192+t];
    out[((size_t)h*192 + t)*nm + m] = s;
  }
}

// ---------------- low-rank kernel (coalesced): kt/mt are [h*192+d][n] ----------------
__global__ __launch_bounds__(256) void lrk_k(const float* __restrict__ qry,
                                             const float* __restrict__ kt,
                                             const float* __restrict__ mt,
                                             const float* __restrict__ jscale,
                                             __bf16* __restrict__ out,
                                             int n, int pitch, float scale){
  int h = blockIdx.x / n, i = blockIdx.x % n;
  __shared__ float qs[192];
  int t=threadIdx.x;
  if(t<192) qs[t] = qry[(size_t)i*1536 + h*192 + t];
  __syncthreads();
  int j = t;
  if(j < n){
    int m = abs(i-j);
    const float* kp = kt + (size_t)h*192*n;
    const float* mp = mt + (size_t)h*192*n;
    float s=0.f;
    #pragma unroll 4
    for(int d=0;d<192;d++) s += qs[d] * kp[(size_t)d*n + j] * mp[(size_t)d*n + m];
    s = (s>=0.f) ? s : 0.2f*s;
    if(jscale) s *= jscale[j];
    out[((size_t)h*pitch + i)*pitch + j] = (__bf16)(s*scale);
  }
}

// ---------------- apply1 MFMA: per (h,m): C[91,64] = klat[h](91x91) @ V(91x64) ----------------
__global__ __launch_bounds__(256) void apply1_mfma(const __bf16* __restrict__ Kl,
                                                   const __bf16* __restrict__ vbf,
                                                   __bf16* __restrict__ u1){
  int h = blockIdx.x / 180, m = blockIdx.x % 180;
  __shared__ __bf16 vst[64][104];
  int t = threadIdx.x;
  const __bf16* src = vbf + ((size_t)(h*180+m)*91)*64;
  for(int idx=t; idx<91*64; idx+=256){
    int j = idx>>6, c = idx&63;
    vst[c][j] = src[idx];
  }
  for(int idx=t; idx<64*13; idx+=256){
    int c = idx/13, j = 91 + idx - (idx/13)*13;
    vst[c][j] = (__bf16)0.f;
  }
  __syncthreads();
  int lane = t & 63, wave = t>>6;
  int m16 = lane & 15, quad = lane>>4;
  floatx4 acc[6];
  #pragma unroll
  for(int i=0;i<6;i++) acc[i]=(floatx4)0.f;
  const __bf16* Ab = Kl + (size_t)h*96*96;
  #pragma unroll
  for(int kc=0; kc<3; kc++){
    bf16x8 bfrag = *(const bf16x8*)&vst[wave*16 + m16][kc*32 + quad*8];
    #pragma unroll
    for(int ti=0;ti<6;ti++){
      bf16x8 afrag = *(const bf16x8*)&Ab[(size_t)(ti*16+m16)*96 + kc*32 + quad*8];
      acc[ti] = __builtin_amdgcn_mfma_f32_16x16x32_bf16(afrag, bfrag, acc[ti], 0,0,0);
    }
  }
  #pragma unroll
  for(int ti=0;ti<6;ti++){
    #pragma unroll
    for(int reg=0;reg<4;reg++){
      int i = ti*16 + quad*4 + reg;
      if(i<91){
        int c = wave*16 + m16;
        u1[(((size_t)(h*91+i)*180)+m)*64 + c] = (__bf16)acc[ti][reg];
      }
    }
  }
}

// ---------------- apply2 MFMA + fused GN2 partial stats ----------------
__global__ __launch_bounds__(256) void apply2_mfma(const __bf16* __restrict__ Kg,
                                                   const __bf16* __restrict__ u1,
                                                   float* __restrict__ uphi,
                                                   float* __restrict__ part2){
  int h = blockIdx.x / 91, i = blockIdx.x % 91;
  __shared__ __bf16 vst[64][208];
  __shared__ float rs[256], rq[256];
  int t = threadIdx.x;
  const __bf16* src = u1 + ((size_t)(h*91+i)*180)*64;
  for(int idx=t; idx<180*64; idx+=256){
    int m = idx>>6, c = idx&63;
    vst[c][m] = src[idx];
  }
  for(int idx=t; idx<64*28; idx+=256){
    int c = idx/28, m = 180 + idx - (idx/28)*28;
    vst[c][m] = (__bf16)0.f;
  }
  __syncthreads();
  int lane = t&63, wave = t>>6;
  int m16 = lane&15, quad = lane>>4;
  floatx4 acc[12];
  #pragma unroll
  for(int l=0;l<12;l++) acc[l]=(floatx4)0.f;
  const __bf16* Ab = Kg + (size_t)h*192*192;
  for(int kc=0; kc<6; kc++){
    bf16x8 bfrag = *(const bf16x8*)&vst[wave*16+m16][kc*32 + quad*8];
    #pragma unroll
    for(int tl=0; tl<12; tl++){
      bf16x8 afrag = *(const bf16x8*)&Ab[(size_t)(tl*16+m16)*192 + kc*32 + quad*8];
      acc[tl] = __builtin_amdgcn_mfma_f32_16x16x32_bf16(afrag, bfrag, acc[tl], 0,0,0);
    }
  }
  float s=0.f, q=0.f;
  #pragma unroll
  for(int tl=0; tl<12; tl++){
    #pragma unroll
    for(int reg=0; reg<4; reg++){
      int l = tl*16 + quad*4 + reg;
      if(l<180){
        int c = wave*16+m16;
        float v = acc[tl][reg];
        uphi[((size_t)i*180 + l)*512 + h*64 + c] = v;
        s += v; q += v*v;
      }
    }
  }
  rs[t]=s; rq[t]=q;
  __syncthreads();
  for(int st=128; st>0; st>>=1){ if(t<st){ rs[t]+=rs[t+st]; rq[t]+=rq[t+st]; } __syncthreads(); }
  if(t==0){ part2[blockIdx.x*2+0]=rs[0]; part2[blockIdx.x*2+1]=rq[0]; }
}

// ---------------------------------------------------------------------------
extern "C" void kernel_launch(void* const* d_in, const int* in_sizes, int n_in,
                              void* d_out, int out_size, void* d_ws, size_t ws_size,
                              hipStream_t stream){
  const float* u_src      = (const float*)d_in[0];
  const float* u_lat_qry  = (const float*)d_in[1];
  const float* u_long_qry = (const float*)d_in[2];
  const float* lat = (const float*)d_in[3];
  const float* lon = (const float*)((in_sizes[4]==180)? d_in[4] : d_in[5]);
  const float* cm_gn_w = (const float*)d_in[7];
  const float* cm_gn_b = (const float*)d_in[8];
  const float* cm_w1   = (const float*)d_in[9];
  const float* cm_b1   = (const float*)d_in[10];
  const float* cm_w2   = (const float*)d_in[11];
  const float* cm_b2   = (const float*)d_in[12];
  const float* tl_in_w = (const float*)d_in[13];
  const float* tl_ln_w = (const float*)d_in[14];
  const float* tl_ln_b = (const float*)d_in[15];
  const float* tl_w1   = (const float*)d_in[16];
  const float* tl_b1   = (const float*)d_in[17];
  const float* tl_w2   = (const float*)d_in[18];
  const float* tl_b2   = (const float*)d_in[19];
  const float* ta_in_w = (const float*)d_in[20];
  const float* ta_ln_w = (const float*)d_in[21];
  const float* ta_ln_b = (const float*)d_in[22];
  const float* ta_w1   = (const float*)d_in[23];
  const float* ta_b1   = (const float*)d_in[24];
  const float* ta_w2   = (const float*)d_in[25];
  const float* ta_b2   = (const float*)d_in[26];
  const float* klong_wk= (const float*)d_in[27];
  const float* klat_wk = (const float*)d_in[28];
  const float* pe_long_freq = (const float*)d_in[29];
  const float* pe_long_w    = (const float*)d_in[30];
  const float* pe_lat_freq  = (const float*)d_in[31];
  const float* pe_lat_w     = (const float*)d_in[32];
  const float* mh_gn_w = (const float*)d_in[33];
  const float* mh_gn_b = (const float*)d_in[34];
  const float* mh_w    = (const float*)d_in[35];

  float* ws = (float*)d_ws;
  const size_t OFF_PART1  = 0;          // 15360
  const size_t OFF_GN1    = 16384;      // 64
  const size_t OFF_WLAT   = 16512;      // 91
  const size_t OFF_MEANLAT= 16640;      // 46080
  const size_t OFF_MEANLON= 62720;      // 23296
  const size_t OFF_ULSRC  = 155392;     // 46080
  const size_t OFF_UASRC  = 201472;     // 23296
  const size_t OFF_KLKL   = 224768;     // 276480 fp32 kprojT long [1536][180]
  const size_t OFF_KLKA   = 501248;     // 139776 fp32 kprojT lat  [1536][91]
  const size_t OFF_MODUL  = 641024;     // 276480 fp32 modT long [1536][180]
  const size_t OFF_MODUA  = 917504;     // 139776 fp32 modT lat  [1536][91]
  const size_t OFF_KBL    = 1057280;    // bf16 8*96*96   -> 36864 f
  const size_t OFF_KBG    = 1094144;    // bf16 8*192*192 -> 147456 f -> ends 1241600
  const size_t OFF_PART2  = 1241600;    // 1456 (728 blocks x 2)
  const size_t OFF_GN2    = 1245440;    // 16
  const size_t OFF_WT1    = 1245456;    // bf16 cm_w1^T -> 131072 f
  const size_t OFF_WT2    = 1376528;    // bf16 cm_w2^T -> 393216 f
  const size_t OFF_WT3    = 1769744;    // bf16 mh_w^T  -> 65536 f -> ends 1835280
  const size_t OFF_VBF    = 1835280;    // bf16 [8][180][91][64] -> 4193280 f -> ends 6028560
  const size_t OFF_A2     = 1835280;    // bf16 16380x512 (GN2'd uphi) reuses VBF post-apply1
  const size_t OFF_U2     = 6028560;    // fp32 16380x768 -> ends 18608400
  const size_t OFF_UPHI   = 6028560;    // fp32 16380x512 (reuses U2)
  const size_t OFF_H1     = 18608400;   // bf16 16380x1024 -> ends 26994960
  const size_t OFF_U1     = 18608400;   // bf16 (reuses H1)
  const size_t OFF_A1     = 26994960;   // bf16 16380x256 -> 2096640 f -> ends 29091600 (~116MB)

  const int NPOS = 16380;

  // 0) weight cvt + zero-fill padded K buffers
  wcvt_k<<<(256*1024+255)/256,256,0,stream>>>(cm_w1, (__bf16*)(ws+OFF_WT1), 256, 1024);
  wcvt_k<<<(1024*768+255)/256,256,0,stream>>>(cm_w2, (__bf16*)(ws+OFF_WT2), 1024, 768);
  wcvt_k<<<(512*256+255)/256,256,0,stream>>>(mh_w,  (__bf16*)(ws+OFF_WT3), 512, 256);
  zfill_bf16<<<(368640+255)/256,256,0,stream>>>((__bf16*)(ws+OFF_KBL), 368640);

  // 1) GN1 stats + cast A1 = bf16(GN1(u_src))
  gn1_partial<<<240,256,0,stream>>>(u_src, ws+OFF_PART1, NPOS);
  gn_final<<<1,64,0,stream>>>(ws+OFF_PART1, ws+OFF_GN1, 240, 32, 1.f/131040.f);
  gncast_k<<<(NPOS*256/4+255)/256,256,0,stream>>>(u_src, ws+OFF_GN1, cm_gn_w, cm_gn_b,
      (__bf16*)(ws+OFF_A1), NPOS*256, 255, 3);

  // 2) h1 = gelu(A1 @ cm_w1 + cm_b1)  [16380 x 1024] bf16
  gemm_ld<1,1><<<dim3(8,128),256,0,stream>>>((const __bf16*)(ws+OFF_A1),
      (const __bf16*)(ws+OFF_WT1), cm_b1, ws+OFF_H1, nullptr, NPOS, 1024, 256);

  // 3) u2 = h1 @ cm_w2 + cm_b2: cols<512 -> bf16 vbf; cols>=512 -> fp32 u2
  gemm_ld<0,2><<<dim3(6,128),256,0,stream>>>((const __bf16*)(ws+OFF_H1),
      (const __bf16*)(ws+OFF_WT2), cm_b2, ws+OFF_U2, (__bf16*)(ws+OFF_VBF), NPOS, 768, 1024);

  // 4) latitude weights
  wlat_k<<<1,128,0,stream>>>(lat, ws+OFF_WLAT, 91);

  // 5) pooling means (u_mid channels)
  mean_over_lat<<<180,256,0,stream>>>(ws+OFF_U2, ws+OFF_MEANLAT);
  mean_over_lon<<<91,256,0,stream>>>(ws+OFF_U2, ws+OFF_MEANLON);

  // 6+7) fused pooling MLPs
  fused_pool_mlp<<<180,256,0,stream>>>(ws+OFF_MEANLAT, nullptr,     tl_in_w, tl_ln_w, tl_ln_b,
      tl_w1, tl_b1, tl_w2, tl_b2, ws+OFF_ULSRC);
  fused_pool_mlp<<<91,256,0,stream>>>(ws+OFF_MEANLON, ws+OFF_WLAT, ta_in_w, ta_ln_w, ta_ln_b,
      ta_w1, ta_b1, ta_w2, ta_b2, ws+OFF_UASRC);

  // 8) k-projections -> transposed [1536][R]
  rowmm_kT<<<dim3(180,6),256,0,stream>>>(ws+OFF_ULSRC, klong_wk, ws+OFF_KLKL, 1536, 180);
  rowmm_kT<<<dim3(91,6), 256,0,stream>>>(ws+OFF_UASRC, klat_wk,  ws+OFF_KLKA, 1536, 91);

  // 9) modulation tables -> transposed [1536][nm]
  modu_k<<<8*180,192,0,stream>>>(lon, pe_long_freq, pe_long_w, ws+OFF_MODUL, 180, 64, 1);
  modu_k<<<8*91, 192,0,stream>>>(lat, pe_lat_freq,  pe_lat_w,  ws+OFF_MODUA, 91, 32, 0);

  // 10) low-rank kernels -> padded bf16
  lrk_k<<<8*180,256,0,stream>>>(u_long_qry, ws+OFF_KLKL, ws+OFF_MODUL, nullptr,
      (__bf16*)(ws+OFF_KBG), 180, 192, 2.f*PI_F/180.f);
  lrk_k<<<8*91, 256,0,stream>>>(u_lat_qry,  ws+OFF_KLKA, ws+OFF_MODUA, ws+OFF_WLAT,
      (__bf16*)(ws+OFF_KBL), 91, 96, PI_F/91.f);

  // 11) kernel application (MFMA); apply2 also emits GN2 partial stats
  apply1_mfma<<<8*180,256,0,stream>>>((const __bf16*)(ws+OFF_KBL), (const __bf16*)(ws+OFF_VBF),
      (__bf16*)(ws+OFF_U1));
  apply2_mfma<<<8*91, 256,0,stream>>>((const __bf16*)(ws+OFF_KBG), (const __bf16*)(ws+OFF_U1),
      ws+OFF_UPHI, ws+OFF_PART2);

  // 12) GN2 finalize + cast A2 + final projection
  gn_final2<<<1,64,0,stream>>>(ws+OFF_PART2, ws+OFF_GN2, 1.f/1048320.f);
  gncast_k<<<(NPOS*512/4+255)/256,256,0,stream>>>(ws+OFF_UPHI, ws+OFF_GN2, mh_gn_w, mh_gn_b,
      (__bf16*)(ws+OFF_A2), NPOS*512, 511, 6);
  gemm_ld<0,0><<<dim3(2,128),256,0,stream>>>((const __bf16*)(ws+OFF_A2),
      (const __bf16*)(ws+OFF_WT3), nullptr, (float*)d_out, nullptr, NPOS, 256, 512);
}

// Round 6
// 507.314 us; speedup vs baseline: 3.6323x; 1.2164x over previous
//
#include <hip/hip_runtime.h>
#include <math.h>

#define PI_F 3.14159265358979323846f

typedef __bf16  bf16x8  __attribute__((ext_vector_type(8)));
typedef float   floatx4 __attribute__((ext_vector_type(4)));

__device__ __forceinline__ float gelu_tanh(float x){
  float x3 = x*x*x;
  float t = tanhf(0.7978845608028654f*(x + 0.044715f*x3));
  return 0.5f*x*(1.0f+t);
}

// async global->LDS 16B per lane; LDS dest = wave-uniform base + lane*16
__device__ __forceinline__ void gl_lds16(const void* g, void* l){
  __builtin_amdgcn_global_load_lds(
      (const __attribute__((address_space(1))) void*)(uintptr_t)g,
      (__attribute__((address_space(3))) void*)(uintptr_t)l,
      16, 0, 0);
}

// ---------------- prep: zfill K buffers + wcvt cm_w2 + wlat (one dispatch) ----------------
__global__ __launch_bounds__(256) void prep_k(const float* __restrict__ w2in,
                                              __bf16* __restrict__ wt2,
                                              __bf16* __restrict__ kbuf,
                                              const float* __restrict__ lat,
                                              float* __restrict__ wlat){
  int b = blockIdx.x, t = threadIdx.x;
  if(b < 1440){
    int i = b*256 + t;
    if(i < 368640) kbuf[i] = (__bf16)0.f;
  } else if(b < 4512){
    int idx = (b-1440)*256 + t;   // 786432 total
    int n = idx >> 10, k = idx & 1023;      // wt2[n][k] = w2[k][n], N=768,K=1024
    wt2[idx] = (__bf16)w2in[(size_t)k*768 + n];
  } else {
    if(t < 91) wlat[t] = cosf(lat[t]);
    __syncthreads();
    if(t == 0){
      float dlat = lat[1]-lat[0];
      float s4 = sinf(dlat*0.25f);
      float pw = s4*s4 / sinf(dlat*0.5f);
      if(wlat[0]  < 0.001f) wlat[0]  = pw;
      if(wlat[90] < 0.001f) wlat[90] = pw;
    }
  }
}

// ---------------- GN1 partial stats + plain bf16 cast of u_src ----------------
__global__ __launch_bounds__(256) void gn1cast_k(const float* __restrict__ x,
                                                 __bf16* __restrict__ xa,
                                                 float* __restrict__ part, int npos){
  int c = threadIdx.x;
  float s=0.f, q=0.f;
  for(int p=blockIdx.x; p<npos; p+=gridDim.x){
    float v = x[p*256 + c];
    xa[p*256 + c] = (__bf16)v;
    s += v; q += v*v;
  }
  __shared__ float ss[256], sq[256];
  ss[c]=s; sq[c]=q;
  __syncthreads();
  if((c&7)==0){
    float a=0.f,b=0.f;
    #pragma unroll
    for(int k=0;k<8;k++){ a+=ss[c+k]; b+=sq[c+k]; }
    int g=c>>3;
    part[(blockIdx.x*32+g)*2+0]=a;
    part[(blockIdx.x*32+g)*2+1]=b;
  }
}

__global__ __launch_bounds__(64) void gn_final(const float* __restrict__ part,
                                               float* __restrict__ stats,
                                               int nblk, int ngroups, float invN){
  int g = threadIdx.x;
  if(g<ngroups){
    float s=0.f,q=0.f;
    for(int b=0;b<nblk;b++){ s+=part[(b*ngroups+g)*2+0]; q+=part[(b*ngroups+g)*2+1]; }
    float m = s*invN;
    float v = q*invN - m*m;
    stats[g*2+0]=m;
    stats[g*2+1]=rsqrtf(v+1e-5f);
  }
}

// ---------------- fold GN1 into W1: wt1[n][c]=bf16(s[c]*w1[c][n]); b1'[n]=b1[n]+sum t[c]w1[c][n] ----------------
__global__ __launch_bounds__(256) void w1fix_k(const float* __restrict__ w1,
                                               const float* __restrict__ b1,
                                               const float* __restrict__ stats,
                                               const float* __restrict__ gw,
                                               const float* __restrict__ gb,
                                               __bf16* __restrict__ wt1,
                                               float* __restrict__ b1p){
  int n = blockIdx.x, c = threadIdx.x;
  int g = c>>3;
  float m = stats[g*2+0], r = stats[g*2+1];
  float s = r*gw[c];
  float t = gb[c] - m*s;
  float w = w1[(size_t)c*1024 + n];
  wt1[(size_t)n*256 + c] = (__bf16)(s*w);
  __shared__ float red[256];
  red[c] = t*w; __syncthreads();
  for(int st=128; st>0; st>>=1){ if(c<st) red[c]+=red[c+st]; __syncthreads(); }
  if(c==0) b1p[n] = b1[n] + red[0];
}

// ---------------- fold GN2 into mh_w (stats computed in-block from part2) ----------------
__global__ __launch_bounds__(256) void w3fix_k(const float* __restrict__ mhw,
                                               const float* __restrict__ part2,
                                               const float* __restrict__ gw,
                                               const float* __restrict__ gb,
                                               __bf16* __restrict__ wt3,
                                               float* __restrict__ b3){
  __shared__ float st[16];
  int n = blockIdx.x, t = threadIdx.x;
  if(t<8){
    float s=0.f,q=0.f;
    for(int i=0;i<91;i++){ s+=part2[(t*91+i)*2+0]; q+=part2[(t*91+i)*2+1]; }
    float m = s*(1.f/1048320.f);
    float v = q*(1.f/1048320.f) - m*m;
    st[t*2+0]=m; st[t*2+1]=rsqrtf(v+1e-5f);
  }
  __syncthreads();
  float bp=0.f;
  #pragma unroll
  for(int l=0;l<2;l++){
    int cc = t + l*256;
    int g = cc>>6;
    float m = st[g*2+0], r = st[g*2+1];
    float s = r*gw[cc];
    float tt = gb[cc] - m*s;
    float w = mhw[(size_t)cc*256 + n];
    wt3[(size_t)n*512 + cc] = (__bf16)(s*w);
    bp += tt*w;
  }
  __shared__ float red[256];
  red[t]=bp; __syncthreads();
  for(int stp=128;stp>0;stp>>=1){ if(t<stp) red[t]+=red[t+stp]; __syncthreads(); }
  if(t==0) b3[n]=red[0];
}

// ---------------- MFMA bf16 GEMM: global_load_lds staging + XOR-swizzled LDS ----------------
// C[M,N] = act( A[M,K](bf16) @ B + bias ), B transposed bf16 [N][K].
// 128x128 tile, BK=32, 4 waves 2x2, 4x4 16x16x32 MFMA/wave.
// Swizzle: chunk c of row r stored at phys chunk c ^ ((r>>1)&3)  -> 2-way (free) banks.
// OUTMODE: 0 = fp32 C, 1 = bf16 C, 2 = u2-split (cols<512 -> VB bf16 [h][m][j][c]; cols>=512 -> UM bf16 [pos][256])
template<int ACT, int OUTMODE>
__global__ __launch_bounds__(256) void gemm_ld(const __bf16* __restrict__ A,
                                               const __bf16* __restrict__ Bt,
                                               const float* __restrict__ bias,
                                               void* __restrict__ Cp,
                                               __bf16* __restrict__ VB,
                                               __bf16* __restrict__ UM,
                                               int M, int N, int K)
{
  __shared__ __bf16 As[128][32];
  __shared__ __bf16 Bs[128][32];
  const int tid  = threadIdx.x;
  const int lane = tid & 63, wave = tid >> 6;
  const int row0 = blockIdx.y*128, col0 = blockIdx.x*128;
  const int lrow = lane >> 2;                       // 16 rows per wave-load
  const int csw  = ((lane&3) ^ ((lane>>3)&3)) * 8;  // swizzled source chunk
  const int wr = (wave >> 1)*64, wc = (wave & 1)*64;
  const int m16 = lane & 15, quad = lane >> 4;
  const int pa = (quad ^ ((m16>>1)&3)) * 8;         // swizzled read chunk

  const __bf16* Ag0 = A  + (size_t)(row0 + wave*32 + lrow)*K + csw;
  const __bf16* Ag1 = Ag0 + (size_t)16*K;
  const __bf16* Bg0 = Bt + (size_t)(col0 + wave*32 + lrow)*K + csw;
  const __bf16* Bg1 = Bg0 + (size_t)16*K;
  void* la0 = &As[wave*32     ][0];
  void* la1 = &As[wave*32 + 16][0];
  void* lb0 = &Bs[wave*32     ][0];
  void* lb1 = &Bs[wave*32 + 16][0];

  floatx4 acc[4][4];
  #pragma unroll
  for(int i=0;i<4;i++)
    #pragma unroll
    for(int j=0;j<4;j++) acc[i][j] = (floatx4)0.f;

  const int kiters = K >> 5;
  for(int kk=0; kk<kiters; kk++){
    __syncthreads();
    gl_lds16(Ag0, la0);
    gl_lds16(Ag1, la1);
    gl_lds16(Bg0, lb0);
    gl_lds16(Bg1, lb1);
    Ag0 += 32; Ag1 += 32; Bg0 += 32; Bg1 += 32;
    __syncthreads();

    bf16x8 af[4], bfv[4];
    #pragma unroll
    for(int ti=0;ti<4;ti++) af[ti]  = *(const bf16x8*)&As[wr + ti*16 + m16][pa];
    #pragma unroll
    for(int tj=0;tj<4;tj++) bfv[tj] = *(const bf16x8*)&Bs[wc + tj*16 + m16][pa];
    #pragma unroll
    for(int ti=0;ti<4;ti++)
      #pragma unroll
      for(int tj=0;tj<4;tj++)
        acc[ti][tj] = __builtin_amdgcn_mfma_f32_16x16x32_bf16(af[ti], bfv[tj], acc[ti][tj], 0,0,0);
  }

  #pragma unroll
  for(int ti=0;ti<4;ti++){
    #pragma unroll
    for(int reg=0;reg<4;reg++){
      int gr = row0 + wr + ti*16 + quad*4 + reg;
      if(gr >= M) continue;
      int jj = gr/180, mm = gr - jj*180;   // only used for OUTMODE 2
      #pragma unroll
      for(int tj=0;tj<4;tj++){
        int gc = col0 + wc + tj*16 + m16;
        float v = acc[ti][tj][reg];
        if(bias) v += bias[gc];
        if(ACT==1) v = gelu_tanh(v);
        if(OUTMODE==2){
          if(gc < 512){
            int hh = gc>>6, cc = gc&63;
            VB[(((size_t)(hh*180+mm)*91)+jj)*64 + cc] = (__bf16)v;
          } else {
            UM[(size_t)gr*256 + (gc-512)] = (__bf16)v;
          }
        } else if(OUTMODE==1){
          ((__bf16*)Cp)[(size_t)gr*N + gc] = (__bf16)v;
        } else {
          ((float*)Cp)[(size_t)gr*N + gc]  = v;
        }
      }
    }
  }
}

// ---------------- merged means over u_mid (bf16): b<180 -> per-lon (over j); else per-lat (over m) ----------------
__global__ __launch_bounds__(256) void means_k(const __bf16* __restrict__ um,
                                               float* __restrict__ mlon_axis,
                                               float* __restrict__ mlat_axis){
  int b = blockIdx.x, c = threadIdx.x;
  if(b < 180){
    float s=0.f;
    for(int j=0;j<91;j++) s += (float)um[(size_t)(j*180+b)*256 + c];
    mlon_axis[b*256+c] = s*(1.0f/91.0f);
  } else {
    int latr = b-180;
    const __bf16* base = um + (size_t)latr*180*256 + c;
    float s=0.f;
    for(int m=0;m<180;m++) s += (float)base[(size_t)m*256];
    mlat_axis[latr*256+c] = s*(1.0f/180.0f);
  }
}

// ---------------- fused pooling reducer body ----------------
__device__ __forceinline__ void pool_body(int r, int t,
    const float* __restrict__ x, const float* __restrict__ rs,
    const float* __restrict__ inw,
    const float* __restrict__ lnw, const float* __restrict__ lnb,
    const float* __restrict__ w1, const float* __restrict__ b1,
    const float* __restrict__ w2, const float* __restrict__ b2,
    float* __restrict__ out,
    float* xs, float* xn, float* red, float* g){
  xs[t] = x[r*256+t];
  __syncthreads();
  float y=0.f;
  for(int c=0;c<256;c++) y += xs[c]*inw[c*256+t];
  if(rs) y *= rs[r];
  red[t]=y; __syncthreads();
  for(int s=128;s>0;s>>=1){ if(t<s) red[t]+=red[t+s]; __syncthreads(); }
  float m = red[0]*(1.f/256.f); __syncthreads();
  float d = y-m; red[t]=d*d; __syncthreads();
  for(int s=128;s>0;s>>=1){ if(t<s) red[t]+=red[t+s]; __syncthreads(); }
  float var = red[0]*(1.f/256.f);
  __syncthreads();
  xn[t] = d*rsqrtf(var+1e-5f)*lnw[t]+lnb[t];
  __syncthreads();
  float s1=b1[t], s2=b1[256+t];
  for(int c=0;c<256;c++){ float xv=xn[c]; s1 += xv*w1[c*512+t]; s2 += xv*w1[c*512+256+t]; }
  g[t] = gelu_tanh(s1)*s2;
  __syncthreads();
  float o=b2[t];
  for(int c=0;c<256;c++) o += g[c]*w2[c*256+t];
  out[r*256+t]=o;
}

__global__ __launch_bounds__(256) void pool2_k(
    const float* __restrict__ mlon_axis, const float* __restrict__ mlat_axis,
    const float* __restrict__ wlat,
    const float* __restrict__ tl_inw, const float* __restrict__ tl_lnw, const float* __restrict__ tl_lnb,
    const float* __restrict__ tl_w1, const float* __restrict__ tl_b1,
    const float* __restrict__ tl_w2, const float* __restrict__ tl_b2,
    const float* __restrict__ ta_inw, const float* __restrict__ ta_lnw, const float* __restrict__ ta_lnb,
    const float* __restrict__ ta_w1, const float* __restrict__ ta_b1,
    const float* __restrict__ ta_w2, const float* __restrict__ ta_b2,
    float* __restrict__ ulsrc, float* __restrict__ uasrc){
  __shared__ float xs[256], xn[256], red[256], g[256];
  int b = blockIdx.x, t = threadIdx.x;
  if(b < 180)
    pool_body(b, t, mlon_axis, nullptr, tl_inw, tl_lnw, tl_lnb, tl_w1, tl_b1, tl_w2, tl_b2,
              ulsrc, xs, xn, red, g);
  else
    pool_body(b-180, t, mlat_axis, wlat, ta_inw, ta_lnw, ta_lnb, ta_w1, ta_b1, ta_w2, ta_b2,
              uasrc, xs, xn, red, g);
}

// ---------------- merged k-projection, transposed output out[col][r] ----------------
__global__ __launch_bounds__(256) void rowmmT2_k(const float* __restrict__ ulsrc,
                                                 const float* __restrict__ uasrc,
                                                 const float* __restrict__ wlong,
                                                 const float* __restrict__ wlatk,
                                                 float* __restrict__ klkl,
                                                 float* __restrict__ klka){
  int b = blockIdx.x, t = threadIdx.x;
  const float* X; const float* W; float* out; int r, R;
  if(b < 180){ r=b;     X=ulsrc; W=wlong; out=klkl; R=180; }
  else       { r=b-180; X=uasrc; W=wlatk; out=klka; R=91;  }
  int j = blockIdx.y*256 + t;
  __shared__ float xs[256];
  xs[t] = X[r*256 + t];
  __syncthreads();
  float s = 0.f;
  for(int c=0;c<256;c++) s += xs[c]*W[(size_t)c*1536 + j];
  out[(size_t)j*R + r] = s;
}

// ---------------- merged modulation tables, transposed out[(h*192+d)][m] ----------------
__global__ __launch_bounds__(256) void modu2_k(const float* __restrict__ lon,
                                               const float* __restrict__ lat,
                                               const float* __restrict__ flong,
                                               const float* __restrict__ flat,
                                               const float* __restrict__ wlong,
                                               const float* __restrict__ wlatm,
                                               float* __restrict__ modul,
                                               float* __restrict__ modua){
  int b = blockIdx.x, t = threadIdx.x;
  const float* coord; const float* freqs; const float* W; float* out;
  int h, m, nm, nk, periodic;
  if(b < 1440){ h=b/180; m=b%180; nm=180; nk=64; periodic=1; coord=lon; freqs=flong; W=wlong; out=modul; }
  else        { int b2=b-1440; h=b2/91; m=b2%91; nm=91; nk=32; periodic=0; coord=lat; freqs=flat; W=wlatm; out=modua; }
  __shared__ float basis[64];
  float dist = fabsf(coord[m] - coord[0]);
  if(periodic && dist > PI_F) dist = 2.f*PI_F - dist;
  float d = dist + 1e-5f;
  if(t < nk) basis[t] = 0.7978845608028654f * sinf(freqs[t]*d/PI_F) / d;
  __syncthreads();
  if(t < 192){
    float s=0.f;
    for(int k=0;k<nk;k++) s += basis[k]*W[(size_t)(k*8+h)*192+t];
    out[((size_t)h*192 + t)*nm + m] = s;
  }
}

// ---------------- merged low-rank kernels (coalesced d-major loads) -> padded bf16 ----------------
__global__ __launch_bounds__(256) void lrk2_k(const float* __restrict__ qlong,
                                              const float* __restrict__ qlat,
                                              const float* __restrict__ klkl,
                                              const float* __restrict__ klka,
                                              const float* __restrict__ modul,
                                              const float* __restrict__ modua,
                                              const float* __restrict__ wlat,
                                              __bf16* __restrict__ kbg,
                                              __bf16* __restrict__ kbl){
  int b = blockIdx.x, t = threadIdx.x;
  const float* qry; const float* kt; const float* mt; const float* js; __bf16* out;
  int h, i, n, pitch; float scale;
  if(b < 1440){ h=b/180; i=b%180; n=180; pitch=192; qry=qlong; kt=klkl; mt=modul; js=nullptr; out=kbg; scale=2.f*PI_F/180.f; }
  else        { int b2=b-1440; h=b2/91; i=b2%91; n=91; pitch=96; qry=qlat; kt=klka; mt=modua; js=wlat; out=kbl; scale=PI_F/91.f; }
  __shared__ float qs[192];
  if(t<192) qs[t] = qry[(size_t)i*1536 + h*192 + t];
  __syncthreads();
  int j = t;
  if(j < n){
    int m = abs(i-j);
    const float* kp = kt + (size_t)h*192*n;
    const float* mp = mt + (size_t)h*192*n;
    float s=0.f;
    #pragma unroll 4
    for(int d=0;d<192;d++) s += qs[d] * kp[(size_t)d*n + j] * mp[(size_t)d*n + m];
    s = (s>=0.f) ? s : 0.2f*s;
    if(js) s *= js[j];
    out[((size_t)h*pitch + i)*pitch + j] = (__bf16)(s*scale);
  }
}

// ---------------- apply1 MFMA: per (h,m): C[91,64] = klat[h](91x91) @ V(91x64) ----------------
__global__ __launch_bounds__(256) void apply1_mfma(const __bf16* __restrict__ Kl,
                                                   const __bf16* __restrict__ vbf,
                                                   __bf16* __restrict__ u1){
  int h = blockIdx.x / 180, m = blockIdx.x % 180;
  __shared__ __bf16 vst[64][104];
  int t = threadIdx.x;
  const __bf16* src = vbf + ((size_t)(h*180+m)*91)*64;
  for(int idx=t; idx<91*64; idx+=256){
    int j = idx>>6, c = idx&63;
    vst[c][j] = src[idx];
  }
  for(int idx=t; idx<64*13; idx+=256){
    int c = idx/13, j = 91 + idx - (idx/13)*13;
    vst[c][j] = (__bf16)0.f;
  }
  __syncthreads();
  int lane = t & 63, wave = t>>6;
  int m16 = lane & 15, quad = lane>>4;
  floatx4 acc[6];
  #pragma unroll
  for(int i=0;i<6;i++) acc[i]=(floatx4)0.f;
  const __bf16* Ab = Kl + (size_t)h*96*96;
  #pragma unroll
  for(int kc=0; kc<3; kc++){
    bf16x8 bfrag = *(const bf16x8*)&vst[wave*16 + m16][kc*32 + quad*8];
    #pragma unroll
    for(int ti=0;ti<6;ti++){
      bf16x8 afrag = *(const bf16x8*)&Ab[(size_t)(ti*16+m16)*96 + kc*32 + quad*8];
      acc[ti] = __builtin_amdgcn_mfma_f32_16x16x32_bf16(afrag, bfrag, acc[ti], 0,0,0);
    }
  }
  #pragma unroll
  for(int ti=0;ti<6;ti++){
    #pragma unroll
    for(int reg=0;reg<4;reg++){
      int i = ti*16 + quad*4 + reg;
      if(i<91){
        int c = wave*16 + m16;
        u1[(((size_t)(h*91+i)*180)+m)*64 + c] = (__bf16)acc[ti][reg];
      }
    }
  }
}

// ---------------- apply2 MFMA: writes A2 bf16 [pos][512] + GN2 partial stats ----------------
__global__ __launch_bounds__(256) void apply2_mfma(const __bf16* __restrict__ Kg,
                                                   const __bf16* __restrict__ u1,
                                                   __bf16* __restrict__ a2,
                                                   float* __restrict__ part2){
  int h = blockIdx.x / 91, i = blockIdx.x % 91;
  __shared__ __bf16 vst[64][208];
  __shared__ float rs[256], rq[256];
  int t = threadIdx.x;
  const __bf16* src = u1 + ((size_t)(h*91+i)*180)*64;
  for(int idx=t; idx<180*64; idx+=256){
    int m = idx>>6, c = idx&63;
    vst[c][m] = src[idx];
  }
  for(int idx=t; idx<64*28; idx+=256){
    int c = idx/28, m = 180 + idx - (idx/28)*28;
    vst[c][m] = (__bf16)0.f;
  }
  __syncthreads();
  int lane = t&63, wave = t>>6;
  int m16 = lane&15, quad = lane>>4;
  floatx4 acc[12];
  #pragma unroll
  for(int l=0;l<12;l++) acc[l]=(floatx4)0.f;
  const __bf16* Ab = Kg + (size_t)h*192*192;
  for(int kc=0; kc<6; kc++){
    bf16x8 bfrag = *(const bf16x8*)&vst[wave*16+m16][kc*32 + quad*8];
    #pragma unroll
    for(int tl=0; tl<12; tl++){
      bf16x8 afrag = *(const bf16x8*)&Ab[(size_t)(tl*16+m16)*192 + kc*32 + quad*8];
      acc[tl] = __builtin_amdgcn_mfma_f32_16x16x32_bf16(afrag, bfrag, acc[tl], 0,0,0);
    }
  }
  float s=0.f, q=0.f;
  #pragma unroll
  for(int tl=0; tl<12; tl++){
    #pragma unroll
    for(int reg=0; reg<4; reg++){
      int l = tl*16 + quad*4 + reg;
      if(l<180){
        int c = wave*16+m16;
        float v = acc[tl][reg];
        a2[((size_t)i*180 + l)*512 + h*64 + c] = (__bf16)v;
        s += v; q += v*v;
      }
    }
  }
  rs[t]=s; rq[t]=q;
  __syncthreads();
  for(int st=128; st>0; st>>=1){ if(t<st){ rs[t]+=rs[t+st]; rq[t]+=rq[t+st]; } __syncthreads(); }
  if(t==0){ part2[blockIdx.x*2+0]=rs[0]; part2[blockIdx.x*2+1]=rq[0]; }
}

// ---------------------------------------------------------------------------
extern "C" void kernel_launch(void* const* d_in, const int* in_sizes, int n_in,
                              void* d_out, int out_size, void* d_ws, size_t ws_size,
                              hipStream_t stream){
  const float* u_src      = (const float*)d_in[0];
  const float* u_lat_qry  = (const float*)d_in[1];
  const float* u_long_qry = (const float*)d_in[2];
  const float* lat = (const float*)d_in[3];
  const float* lon = (const float*)((in_sizes[4]==180)? d_in[4] : d_in[5]);
  const float* cm_gn_w = (const float*)d_in[7];
  const float* cm_gn_b = (const float*)d_in[8];
  const float* cm_w1   = (const float*)d_in[9];
  const float* cm_b1   = (const float*)d_in[10];
  const float* cm_w2   = (const float*)d_in[11];
  const float* cm_b2   = (const float*)d_in[12];
  const float* tl_in_w = (const float*)d_in[13];
  const float* tl_ln_w = (const float*)d_in[14];
  const float* tl_ln_b = (const float*)d_in[15];
  const float* tl_w1   = (const float*)d_in[16];
  const float* tl_b1   = (const float*)d_in[17];
  const float* tl_w2   = (const float*)d_in[18];
  const float* tl_b2   = (const float*)d_in[19];
  const float* ta_in_w = (const float*)d_in[20];
  const float* ta_ln_w = (const float*)d_in[21];
  const float* ta_ln_b = (const float*)d_in[22];
  const float* ta_w1   = (const float*)d_in[23];
  const float* ta_b1   = (const float*)d_in[24];
  const float* ta_w2   = (const float*)d_in[25];
  const float* ta_b2   = (const float*)d_in[26];
  const float* klong_wk= (const float*)d_in[27];
  const float* klat_wk = (const float*)d_in[28];
  const float* pe_long_freq = (const float*)d_in[29];
  const float* pe_long_w    = (const float*)d_in[30];
  const float* pe_lat_freq  = (const float*)d_in[31];
  const float* pe_lat_w     = (const float*)d_in[32];
  const float* mh_gn_w = (const float*)d_in[33];
  const float* mh_gn_b = (const float*)d_in[34];
  const float* mh_w    = (const float*)d_in[35];

  float* ws = (float*)d_ws;
  const size_t OFF_PART1  = 0;          // 15360
  const size_t OFF_GN1    = 16384;      // 64
  const size_t OFF_WLAT   = 16512;      // 91
  const size_t OFF_MEANLON= 16640;      // 46080 (per-lon means)
  const size_t OFF_MEANLAT= 62720;      // 23296 (per-lat means)
  const size_t OFF_ULSRC  = 155392;     // 46080
  const size_t OFF_UASRC  = 201472;     // 23296
  const size_t OFF_KLKL   = 224768;     // 276480 fp32 kprojT long [1536][180]
  const size_t OFF_KLKA   = 501248;     // 139776 fp32 kprojT lat  [1536][91]
  const size_t OFF_MODUL  = 641024;     // 276480 fp32 modT long [1536][180]
  const size_t OFF_MODUA  = 917504;     // 139776 fp32 modT lat  [1536][91]
  const size_t OFF_KBL    = 1057280;    // bf16 8*96*96   -> 36864 f
  const size_t OFF_KBG    = 1094144;    // bf16 8*192*192 -> 147456 f -> ends 1241600
  const size_t OFF_PART2  = 1241600;    // 1456
  const size_t OFF_B1P    = 1243056;    // 1024
  const size_t OFF_B3     = 1244080;    // 256
  const size_t OFF_WT1    = 1245456;    // bf16 [1024][256] -> 131072 f
  const size_t OFF_WT2    = 1376528;    // bf16 [768][1024] -> 393216 f
  const size_t OFF_WT3    = 1769744;    // bf16 [256][512]  -> 65536 f -> ends 1835280
  const size_t OFF_VBF    = 1835280;    // bf16 [8][180][91][64] -> 4193280 f -> ends 6028560
  const size_t OFF_A2     = 1835280;    // bf16 [16380][512] (reuses VBF post-apply1)
  const size_t OFF_UMID   = 6028560;    // bf16 [16380][256] -> 2096640 f
  const size_t OFF_H1     = 18608400;   // bf16 16380x1024 -> ends 26994960
  const size_t OFF_U1     = 18608400;   // bf16 (reuses H1)
  const size_t OFF_A1     = 26994960;   // bf16 16380x256 -> ends 29091600

  const int NPOS = 16380;

  // 1) prep (zfill + wcvt w2 + wlat) -- one dispatch
  prep_k<<<4513,256,0,stream>>>(cm_w2, (__bf16*)(ws+OFF_WT2), (__bf16*)(ws+OFF_KBL),
      lat, ws+OFF_WLAT);

  // 2) GN1 partials + plain bf16 cast of u_src
  gn1cast_k<<<240,256,0,stream>>>(u_src, (__bf16*)(ws+OFF_A1), ws+OFF_PART1, NPOS);
  gn_final<<<1,64,0,stream>>>(ws+OFF_PART1, ws+OFF_GN1, 240, 32, 1.f/131040.f);

  // 3) fold GN1 into W1 (scaled bf16 weights + folded bias)
  w1fix_k<<<1024,256,0,stream>>>(cm_w1, cm_b1, ws+OFF_GN1, cm_gn_w, cm_gn_b,
      (__bf16*)(ws+OFF_WT1), ws+OFF_B1P);

  // 4) h1 = gelu(A1 @ W1' + b1')  [16380 x 1024] bf16
  gemm_ld<1,1><<<dim3(8,128),256,0,stream>>>((const __bf16*)(ws+OFF_A1),
      (const __bf16*)(ws+OFF_WT1), ws+OFF_B1P, ws+OFF_H1, nullptr, nullptr, NPOS, 1024, 256);

  // 5) u2 = h1 @ W2 + b2: cols<512 -> vbf bf16; cols>=512 -> umid bf16
  gemm_ld<0,2><<<dim3(6,128),256,0,stream>>>((const __bf16*)(ws+OFF_H1),
      (const __bf16*)(ws+OFF_WT2), cm_b2, nullptr, (__bf16*)(ws+OFF_VBF),
      (__bf16*)(ws+OFF_UMID), NPOS, 768, 1024);

  // 6) merged means
  means_k<<<271,256,0,stream>>>((const __bf16*)(ws+OFF_UMID), ws+OFF_MEANLON, ws+OFF_MEANLAT);

  // 7) merged pooling MLPs
  pool2_k<<<271,256,0,stream>>>(ws+OFF_MEANLON, ws+OFF_MEANLAT, ws+OFF_WLAT,
      tl_in_w, tl_ln_w, tl_ln_b, tl_w1, tl_b1, tl_w2, tl_b2,
      ta_in_w, ta_ln_w, ta_ln_b, ta_w1, ta_b1, ta_w2, ta_b2,
      ws+OFF_ULSRC, ws+OFF_UASRC);

  // 8) merged k-projections (transposed)
  rowmmT2_k<<<dim3(271,6),256,0,stream>>>(ws+OFF_ULSRC, ws+OFF_UASRC, klong_wk, klat_wk,
      ws+OFF_KLKL, ws+OFF_KLKA);

  // 9) merged modulation tables (transposed)
  modu2_k<<<2168,256,0,stream>>>(lon, lat, pe_long_freq, pe_lat_freq, pe_long_w, pe_lat_w,
      ws+OFF_MODUL, ws+OFF_MODUA);

  // 10) merged low-rank kernels -> padded bf16
  lrk2_k<<<2168,256,0,stream>>>(u_long_qry, u_lat_qry, ws+OFF_KLKL, ws+OFF_KLKA,
      ws+OFF_MODUL, ws+OFF_MODUA, ws+OFF_WLAT, (__bf16*)(ws+OFF_KBG), (__bf16*)(ws+OFF_KBL));

  // 11) kernel application (MFMA); apply2 emits bf16 A2 + GN2 partials
  apply1_mfma<<<8*180,256,0,stream>>>((const __bf16*)(ws+OFF_KBL), (const __bf16*)(ws+OFF_VBF),
      (__bf16*)(ws+OFF_U1));
  apply2_mfma<<<8*91, 256,0,stream>>>((const __bf16*)(ws+OFF_KBG), (const __bf16*)(ws+OFF_U1),
      (__bf16*)(ws+OFF_A2), ws+OFF_PART2);

  // 12) fold GN2 into mh_w, then final projection
  w3fix_k<<<256,256,0,stream>>>(mh_w, ws+OFF_PART2, mh_gn_w, mh_gn_b,
      (__bf16*)(ws+OFF_WT3), ws+OFF_B3);
  gemm_ld<0,0><<<dim3(2,128),256,0,stream>>>((const __bf16*)(ws+OFF_A2),
      (const __bf16*)(ws+OFF_WT3), ws+OFF_B3, (float*)d_out, nullptr, nullptr, NPOS, 256, 512);
}

// Round 7
// 448.926 us; speedup vs baseline: 4.1047x; 1.1301x over previous
//
#include <hip/hip_runtime.h>
#include <math.h>

#define PI_F 3.14159265358979323846f

typedef __bf16  bf16x8  __attribute__((ext_vector_type(8)));
typedef float   floatx4 __attribute__((ext_vector_type(4)));

__device__ __forceinline__ float gelu_tanh(float x){
  float x3 = x*x*x;
  float t = tanhf(0.7978845608028654f*(x + 0.044715f*x3));
  return 0.5f*x*(1.0f+t);
}

// async global->LDS 16B per lane; LDS dest = wave-uniform base + lane*16
__device__ __forceinline__ void gl_lds16(const void* g, void* l){
  __builtin_amdgcn_global_load_lds(
      (const __attribute__((address_space(1))) void*)(uintptr_t)g,
      (__attribute__((address_space(3))) void*)(uintptr_t)l,
      16, 0, 0);
}

// ---------------- prep: zfill K buffers + wcvt cm_w2 + wlat (one dispatch) ----------------
__global__ __launch_bounds__(256) void prep_k(const float* __restrict__ w2in,
                                              __bf16* __restrict__ wt2,
                                              __bf16* __restrict__ kbuf,
                                              const float* __restrict__ lat,
                                              float* __restrict__ wlat){
  int b = blockIdx.x, t = threadIdx.x;
  if(b < 1440){
    int i = b*256 + t;
    if(i < 368640) kbuf[i] = (__bf16)0.f;
  } else if(b < 4512){
    int idx = (b-1440)*256 + t;   // 786432 total
    int n = idx >> 10, k = idx & 1023;      // wt2[n][k] = w2[k][n], N=768,K=1024
    wt2[idx] = (__bf16)w2in[(size_t)k*768 + n];
  } else {
    if(t < 91) wlat[t] = cosf(lat[t]);
    __syncthreads();
    if(t == 0){
      float dlat = lat[1]-lat[0];
      float s4 = sinf(dlat*0.25f);
      float pw = s4*s4 / sinf(dlat*0.5f);
      if(wlat[0]  < 0.001f) wlat[0]  = pw;
      if(wlat[90] < 0.001f) wlat[90] = pw;
    }
  }
}

// ---------------- GN1 partial stats + plain bf16 cast of u_src (512 blocks) ----------------
__global__ __launch_bounds__(256) void gn1cast_k(const float* __restrict__ x,
                                                 __bf16* __restrict__ xa,
                                                 float* __restrict__ part, int npos){
  int c = threadIdx.x;
  float s=0.f, q=0.f;
  for(int p=blockIdx.x; p<npos; p+=gridDim.x){
    float v = x[p*256 + c];
    xa[p*256 + c] = (__bf16)v;
    s += v; q += v*v;
  }
  __shared__ float ss[256], sq[256];
  ss[c]=s; sq[c]=q;
  __syncthreads();
  if((c&7)==0){
    float a=0.f,b=0.f;
    #pragma unroll
    for(int k=0;k<8;k++){ a+=ss[c+k]; b+=sq[c+k]; }
    int g=c>>3;
    part[(blockIdx.x*32+g)*2+0]=a;
    part[(blockIdx.x*32+g)*2+1]=b;
  }
}

// ---------------- parallel GN final reduce: 256 threads, 8 chunks per group ----------------
__global__ __launch_bounds__(256) void gn_final_par(const float* __restrict__ part,
                                                    float* __restrict__ stats,
                                                    int nblk, float invN){
  // ngroups = 32 fixed
  int t = threadIdx.x;
  int g = t & 31, ch = t >> 5;       // 8 chunks
  float s=0.f,q=0.f;
  for(int b=ch; b<nblk; b+=8){
    s += part[(b*32+g)*2+0];
    q += part[(b*32+g)*2+1];
  }
  __shared__ float ss[256], sq[256];
  ss[t]=s; sq[t]=q;
  __syncthreads();
  if(t<32){
    float a=0.f,bq=0.f;
    #pragma unroll
    for(int c=0;c<8;c++){ a+=ss[c*32+t]; bq+=sq[c*32+t]; }
    float m = a*invN;
    float v = bq*invN - m*m;
    stats[t*2+0]=m;
    stats[t*2+1]=rsqrtf(v+1e-5f);
  }
}

// ---------------- fold GN1 into W1 ----------------
__global__ __launch_bounds__(256) void w1fix_k(const float* __restrict__ w1,
                                               const float* __restrict__ b1,
                                               const float* __restrict__ stats,
                                               const float* __restrict__ gw,
                                               const float* __restrict__ gb,
                                               __bf16* __restrict__ wt1,
                                               float* __restrict__ b1p){
  int n = blockIdx.x, c = threadIdx.x;
  int g = c>>3;
  float m = stats[g*2+0], r = stats[g*2+1];
  float s = r*gw[c];
  float t = gb[c] - m*s;
  float w = w1[(size_t)c*1024 + n];
  wt1[(size_t)n*256 + c] = (__bf16)(s*w);
  __shared__ float red[256];
  red[c] = t*w; __syncthreads();
  for(int st=128; st>0; st>>=1){ if(c<st) red[c]+=red[c+st]; __syncthreads(); }
  if(c==0) b1p[n] = b1[n] + red[0];
}

// ---------------- fold GN2 into mh_w (parallel in-block stats from part2) ----------------
__global__ __launch_bounds__(256) void w3fix_k(const float* __restrict__ mhw,
                                               const float* __restrict__ part2,
                                               const float* __restrict__ gw,
                                               const float* __restrict__ gb,
                                               __bf16* __restrict__ wt3,
                                               float* __restrict__ b3){
  __shared__ float st[16];
  __shared__ float ps[256], pq[256];
  int n = blockIdx.x, t = threadIdx.x;
  {
    int g = t & 7, ch = t >> 3;      // 32 chunks per group
    float s=0.f,q=0.f;
    for(int i=ch; i<91; i+=32){
      s += part2[(g*91+i)*2+0];
      q += part2[(g*91+i)*2+1];
    }
    ps[t]=s; pq[t]=q;
    __syncthreads();
    if(t<8){
      float a=0.f,bq=0.f;
      #pragma unroll
      for(int c=0;c<32;c++){ a+=ps[c*8+t]; bq+=pq[c*8+t]; }
      float m = a*(1.f/1048320.f);
      float v = bq*(1.f/1048320.f) - m*m;
      st[t*2+0]=m; st[t*2+1]=rsqrtf(v+1e-5f);
    }
    __syncthreads();
  }
  float bp=0.f;
  #pragma unroll
  for(int l=0;l<2;l++){
    int cc = t + l*256;
    int g = cc>>6;
    float m = st[g*2+0], r = st[g*2+1];
    float s = r*gw[cc];
    float tt = gb[cc] - m*s;
    float w = mhw[(size_t)cc*256 + n];
    wt3[(size_t)n*512 + cc] = (__bf16)(s*w);
    bp += tt*w;
  }
  __shared__ float red[256];
  red[t]=bp; __syncthreads();
  for(int stp=128;stp>0;stp>>=1){ if(t<stp) red[t]+=red[t+stp]; __syncthreads(); }
  if(t==0) b3[n]=red[0];
}

// ---------------- MFMA bf16 GEMM: global_load_lds staging + XOR-swizzled LDS ----------------
// Grid: (row, col) with row = blockIdx.x (fastest) so all col-blocks of one A-row-tile
// land on one XCD (linear id = col*128+row; 128%8==0 -> XCD = row%8). A fetched once/XCD.
// OUTMODE: 0 = fp32 C, 1 = bf16 C, 2 = u2-split (cols<512 -> VB bf16 [h][m][j][c]; cols>=512 -> UM bf16 [pos][256])
template<int ACT, int OUTMODE>
__global__ __launch_bounds__(256) void gemm_ld(const __bf16* __restrict__ A,
                                               const __bf16* __restrict__ Bt,
                                               const float* __restrict__ bias,
                                               void* __restrict__ Cp,
                                               __bf16* __restrict__ VB,
                                               __bf16* __restrict__ UM,
                                               int M, int N, int K)
{
  __shared__ __bf16 As[128][32];
  __shared__ __bf16 Bs[128][32];
  const int tid  = threadIdx.x;
  const int lane = tid & 63, wave = tid >> 6;
  const int row0 = blockIdx.x*128, col0 = blockIdx.y*128;
  const int lrow = lane >> 2;                       // 16 rows per wave-load
  const int csw  = ((lane&3) ^ ((lane>>3)&3)) * 8;  // swizzled source chunk
  const int wr = (wave >> 1)*64, wc = (wave & 1)*64;
  const int m16 = lane & 15, quad = lane >> 4;
  const int pa = (quad ^ ((m16>>1)&3)) * 8;         // swizzled read chunk

  const __bf16* Ag0 = A  + (size_t)(row0 + wave*32 + lrow)*K + csw;
  const __bf16* Ag1 = Ag0 + (size_t)16*K;
  const __bf16* Bg0 = Bt + (size_t)(col0 + wave*32 + lrow)*K + csw;
  const __bf16* Bg1 = Bg0 + (size_t)16*K;
  void* la0 = &As[wave*32     ][0];
  void* la1 = &As[wave*32 + 16][0];
  void* lb0 = &Bs[wave*32     ][0];
  void* lb1 = &Bs[wave*32 + 16][0];

  floatx4 acc[4][4];
  #pragma unroll
  for(int i=0;i<4;i++)
    #pragma unroll
    for(int j=0;j<4;j++) acc[i][j] = (floatx4)0.f;

  const int kiters = K >> 5;
  for(int kk=0; kk<kiters; kk++){
    __syncthreads();
    gl_lds16(Ag0, la0);
    gl_lds16(Ag1, la1);
    gl_lds16(Bg0, lb0);
    gl_lds16(Bg1, lb1);
    Ag0 += 32; Ag1 += 32; Bg0 += 32; Bg1 += 32;
    __syncthreads();

    bf16x8 af[4], bfv[4];
    #pragma unroll
    for(int ti=0;ti<4;ti++) af[ti]  = *(const bf16x8*)&As[wr + ti*16 + m16][pa];
    #pragma unroll
    for(int tj=0;tj<4;tj++) bfv[tj] = *(const bf16x8*)&Bs[wc + tj*16 + m16][pa];
    #pragma unroll
    for(int ti=0;ti<4;ti++)
      #pragma unroll
      for(int tj=0;tj<4;tj++)
        acc[ti][tj] = __builtin_amdgcn_mfma_f32_16x16x32_bf16(af[ti], bfv[tj], acc[ti][tj], 0,0,0);
  }

  #pragma unroll
  for(int ti=0;ti<4;ti++){
    #pragma unroll
    for(int reg=0;reg<4;reg++){
      int gr = row0 + wr + ti*16 + quad*4 + reg;
      if(gr >= M) continue;
      int jj = gr/180, mm = gr - jj*180;   // only used for OUTMODE 2
      #pragma unroll
      for(int tj=0;tj<4;tj++){
        int gc = col0 + wc + tj*16 + m16;
        float v = acc[ti][tj][reg];
        if(bias) v += bias[gc];
        if(ACT==1) v = gelu_tanh(v);
        if(OUTMODE==2){
          if(gc < 512){
            int hh = gc>>6, cc = gc&63;
            VB[(((size_t)(hh*180+mm)*91)+jj)*64 + cc] = (__bf16)v;
          } else {
            UM[(size_t)gr*256 + (gc-512)] = (__bf16)v;
          }
        } else if(OUTMODE==1){
          ((__bf16*)Cp)[(size_t)gr*N + gc] = (__bf16)v;
        } else {
          ((float*)Cp)[(size_t)gr*N + gc]  = v;
        }
      }
    }
  }
}

// ---------------- merged means over u_mid (bf16) ----------------
__global__ __launch_bounds__(256) void means_k(const __bf16* __restrict__ um,
                                               float* __restrict__ mlon_axis,
                                               float* __restrict__ mlat_axis){
  int b = blockIdx.x, c = threadIdx.x;
  if(b < 180){
    float s=0.f;
    for(int j=0;j<91;j++) s += (float)um[(size_t)(j*180+b)*256 + c];
    mlon_axis[b*256+c] = s*(1.0f/91.0f);
  } else {
    int latr = b-180;
    const __bf16* base = um + (size_t)latr*180*256 + c;
    float s=0.f;
    for(int m=0;m<180;m++) s += (float)base[(size_t)m*256];
    mlat_axis[latr*256+c] = s*(1.0f/180.0f);
  }
}

// ---------------- fused pooling reducer body ----------------
__device__ __forceinline__ void pool_body(int r, int t,
    const float* __restrict__ x, const float* __restrict__ rs,
    const float* __restrict__ inw,
    const float* __restrict__ lnw, const float* __restrict__ lnb,
    const float* __restrict__ w1, const float* __restrict__ b1,
    const float* __restrict__ w2, const float* __restrict__ b2,
    float* __restrict__ out,
    float* xs, float* xn, float* red, float* g){
  xs[t] = x[r*256+t];
  __syncthreads();
  float y=0.f;
  for(int c=0;c<256;c++) y += xs[c]*inw[c*256+t];
  if(rs) y *= rs[r];
  red[t]=y; __syncthreads();
  for(int s=128;s>0;s>>=1){ if(t<s) red[t]+=red[t+s]; __syncthreads(); }
  float m = red[0]*(1.f/256.f); __syncthreads();
  float d = y-m; red[t]=d*d; __syncthreads();
  for(int s=128;s>0;s>>=1){ if(t<s) red[t]+=red[t+s]; __syncthreads(); }
  float var = red[0]*(1.f/256.f);
  __syncthreads();
  xn[t] = d*rsqrtf(var+1e-5f)*lnw[t]+lnb[t];
  __syncthreads();
  float s1=b1[t], s2=b1[256+t];
  for(int c=0;c<256;c++){ float xv=xn[c]; s1 += xv*w1[c*512+t]; s2 += xv*w1[c*512+256+t]; }
  g[t] = gelu_tanh(s1)*s2;
  __syncthreads();
  float o=b2[t];
  for(int c=0;c<256;c++) o += g[c]*w2[c*256+t];
  out[r*256+t]=o;
}

__global__ __launch_bounds__(256) void pool2_k(
    const float* __restrict__ mlon_axis, const float* __restrict__ mlat_axis,
    const float* __restrict__ wlat,
    const float* __restrict__ tl_inw, const float* __restrict__ tl_lnw, const float* __restrict__ tl_lnb,
    const float* __restrict__ tl_w1, const float* __restrict__ tl_b1,
    const float* __restrict__ tl_w2, const float* __restrict__ tl_b2,
    const float* __restrict__ ta_inw, const float* __restrict__ ta_lnw, const float* __restrict__ ta_lnb,
    const float* __restrict__ ta_w1, const float* __restrict__ ta_b1,
    const float* __restrict__ ta_w2, const float* __restrict__ ta_b2,
    float* __restrict__ ulsrc, float* __restrict__ uasrc){
  __shared__ float xs[256], xn[256], red[256], g[256];
  int b = blockIdx.x, t = threadIdx.x;
  if(b < 180)
    pool_body(b, t, mlon_axis, nullptr, tl_inw, tl_lnw, tl_lnb, tl_w1, tl_b1, tl_w2, tl_b2,
              ulsrc, xs, xn, red, g);
  else
    pool_body(b-180, t, mlat_axis, wlat, ta_inw, ta_lnw, ta_lnb, ta_w1, ta_b1, ta_w2, ta_b2,
              uasrc, xs, xn, red, g);
}

// ---------------- merged k-projection, transposed output out[col][r] ----------------
__global__ __launch_bounds__(256) void rowmmT2_k(const float* __restrict__ ulsrc,
                                                 const float* __restrict__ uasrc,
                                                 const float* __restrict__ wlong,
                                                 const float* __restrict__ wlatk,
                                                 float* __restrict__ klkl,
                                                 float* __restrict__ klka){
  int b = blockIdx.x, t = threadIdx.x;
  const float* X; const float* W; float* out; int r, R;
  if(b < 180){ r=b;     X=ulsrc; W=wlong; out=klkl; R=180; }
  else       { r=b-180; X=uasrc; W=wlatk; out=klka; R=91;  }
  int j = blockIdx.y*256 + t;
  __shared__ float xs[256];
  xs[t] = X[r*256 + t];
  __syncthreads();
  float s = 0.f;
  for(int c=0;c<256;c++) s += xs[c]*W[(size_t)c*1536 + j];
  out[(size_t)j*R + r] = s;
}

// ---------------- merged modulation tables, transposed out[(h*192+d)][m] ----------------
__global__ __launch_bounds__(256) void modu2_k(const float* __restrict__ lon,
                                               const float* __restrict__ lat,
                                               const float* __restrict__ flong,
                                               const float* __restrict__ flat,
                                               const float* __restrict__ wlong,
                                               const float* __restrict__ wlatm,
                                               float* __restrict__ modul,
                                               float* __restrict__ modua){
  int b = blockIdx.x, t = threadIdx.x;
  const float* coord; const float* freqs; const float* W; float* out;
  int h, m, nm, nk, periodic;
  if(b < 1440){ h=b/180; m=b%180; nm=180; nk=64; periodic=1; coord=lon; freqs=flong; W=wlong; out=modul; }
  else        { int b2=b-1440; h=b2/91; m=b2%91; nm=91; nk=32; periodic=0; coord=lat; freqs=flat; W=wlatm; out=modua; }
  __shared__ float basis[64];
  float dist = fabsf(coord[m] - coord[0]);
  if(periodic && dist > PI_F) dist = 2.f*PI_F - dist;
  float d = dist + 1e-5f;
  if(t < nk) basis[t] = 0.7978845608028654f * sinf(freqs[t]*d/PI_F) / d;
  __syncthreads();
  if(t < 192){
    float s=0.f;
    for(int k=0;k<nk;k++) s += basis[k]*W[(size_t)(k*8+h)*192+t];
    out[((size_t)h*192 + t)*nm + m] = s;
  }
}

// ---------------- merged low-rank kernels (coalesced d-major loads) -> padded bf16 ----------------
__global__ __launch_bounds__(256) void lrk2_k(const float* __restrict__ qlong,
                                              const float* __restrict__ qlat,
                                              const float* __restrict__ klkl,
                                              const float* __restrict__ klka,
                                              const float* __restrict__ modul,
                                              const float* __restrict__ modua,
                                              const float* __restrict__ wlat,
                                              __bf16* __restrict__ kbg,
                                              __bf16* __restrict__ kbl){
  int b = blockIdx.x, t = threadIdx.x;
  const float* qry; const float* kt; const float* mt; const float* js; __bf16* out;
  int h, i, n, pitch; float scale;
  if(b < 1440){ h=b/180; i=b%180; n=180; pitch=192; qry=qlong; kt=klkl; mt=modul; js=nullptr; out=kbg; scale=2.f*PI_F/180.f; }
  else        { int b2=b-1440; h=b2/91; i=b2%91; n=91; pitch=96; qry=qlat; kt=klka; mt=modua; js=wlat; out=kbl; scale=PI_F/91.f; }
  __shared__ float qs[192];
  if(t<192) qs[t] = qry[(size_t)i*1536 + h*192 + t];
  __syncthreads();
  int j = t;
  if(j < n){
    int m = abs(i-j);
    const float* kp = kt + (size_t)h*192*n;
    const float* mp = mt + (size_t)h*192*n;
    float s=0.f;
    #pragma unroll 4
    for(int d=0;d<192;d++) s += qs[d] * kp[(size_t)d*n + j] * mp[(size_t)d*n + m];
    s = (s>=0.f) ? s : 0.2f*s;
    if(js) s *= js[j];
    out[((size_t)h*pitch + i)*pitch + j] = (__bf16)(s*scale);
  }
}

// ---------------- apply1 MFMA: per (h,m): C[91,64] = klat[h](91x91) @ V(91x64) ----------------
__global__ __launch_bounds__(256) void apply1_mfma(const __bf16* __restrict__ Kl,
                                                   const __bf16* __restrict__ vbf,
                                                   __bf16* __restrict__ u1){
  int h = blockIdx.x / 180, m = blockIdx.x % 180;
  __shared__ __bf16 vst[64][104];
  int t = threadIdx.x;
  const __bf16* src = vbf + ((size_t)(h*180+m)*91)*64;
  for(int idx=t; idx<91*64; idx+=256){
    int j = idx>>6, c = idx&63;
    vst[c][j] = src[idx];
  }
  for(int idx=t; idx<64*13; idx+=256){
    int c = idx/13, j = 91 + idx - (idx/13)*13;
    vst[c][j] = (__bf16)0.f;
  }
  __syncthreads();
  int lane = t & 63, wave = t>>6;
  int m16 = lane & 15, quad = lane>>4;
  floatx4 acc[6];
  #pragma unroll
  for(int i=0;i<6;i++) acc[i]=(floatx4)0.f;
  const __bf16* Ab = Kl + (size_t)h*96*96;
  #pragma unroll
  for(int kc=0; kc<3; kc++){
    bf16x8 bfrag = *(const bf16x8*)&vst[wave*16 + m16][kc*32 + quad*8];
    #pragma unroll
    for(int ti=0;ti<6;ti++){
      bf16x8 afrag = *(const bf16x8*)&Ab[(size_t)(ti*16+m16)*96 + kc*32 + quad*8];
      acc[ti] = __builtin_amdgcn_mfma_f32_16x16x32_bf16(afrag, bfrag, acc[ti], 0,0,0);
    }
  }
  #pragma unroll
  for(int ti=0;ti<6;ti++){
    #pragma unroll
    for(int reg=0;reg<4;reg++){
      int i = ti*16 + quad*4 + reg;
      if(i<91){
        int c = wave*16 + m16;
        u1[(((size_t)(h*91+i)*180)+m)*64 + c] = (__bf16)acc[ti][reg];
      }
    }
  }
}

// ---------------- apply2 MFMA: writes A2 bf16 [pos][512] + GN2 partial stats ----------------
__global__ __launch_bounds__(256) void apply2_mfma(const __bf16* __restrict__ Kg,
                                                   const __bf16* __restrict__ u1,
                                                   __bf16* __restrict__ a2,
                                                   float* __restrict__ part2){
  int h = blockIdx.x / 91, i = blockIdx.x % 91;
  __shared__ __bf16 vst[64][208];
  __shared__ float rs[256], rq[256];
  int t = threadIdx.x;
  const __bf16* src = u1 + ((size_t)(h*91+i)*180)*64;
  for(int idx=t; idx<180*64; idx+=256){
    int m = idx>>6, c = idx&63;
    vst[c][m] = src[idx];
  }
  for(int idx=t; idx<64*28; idx+=256){
    int c = idx/28, m = 180 + idx - (idx/28)*28;
    vst[c][m] = (__bf16)0.f;
  }
  __syncthreads();
  int lane = t&63, wave = t>>6;
  int m16 = lane&15, quad = lane>>4;
  floatx4 acc[12];
  #pragma unroll
  for(int l=0;l<12;l++) acc[l]=(floatx4)0.f;
  const __bf16* Ab = Kg + (size_t)h*192*192;
  for(int kc=0; kc<6; kc++){
    bf16x8 bfrag = *(const bf16x8*)&vst[wave*16+m16][kc*32 + quad*8];
    #pragma unroll
    for(int tl=0; tl<12; tl++){
      bf16x8 afrag = *(const bf16x8*)&Ab[(size_t)(tl*16+m16)*192 + kc*32 + quad*8];
      acc[tl] = __builtin_amdgcn_mfma_f32_16x16x32_bf16(afrag, bfrag, acc[tl], 0,0,0);
    }
  }
  float s=0.f, q=0.f;
  #pragma unroll
  for(int tl=0; tl<12; tl++){
    #pragma unroll
    for(int reg=0; reg<4; reg++){
      int l = tl*16 + quad*4 + reg;
      if(l<180){
        int c = wave*16+m16;
        float v = acc[tl][reg];
        a2[((size_t)i*180 + l)*512 + h*64 + c] = (__bf16)v;
        s += v; q += v*v;
      }
    }
  }
  rs[t]=s; rq[t]=q;
  __syncthreads();
  for(int st=128; st>0; st>>=1){ if(t<st){ rs[t]+=rs[t+st]; rq[t]+=rq[t+st]; } __syncthreads(); }
  if(t==0){ part2[blockIdx.x*2+0]=rs[0]; part2[blockIdx.x*2+1]=rq[0]; }
}

// ---------------------------------------------------------------------------
extern "C" void kernel_launch(void* const* d_in, const int* in_sizes, int n_in,
                              void* d_out, int out_size, void* d_ws, size_t ws_size,
                              hipStream_t stream){
  const float* u_src      = (const float*)d_in[0];
  const float* u_lat_qry  = (const float*)d_in[1];
  const float* u_long_qry = (const float*)d_in[2];
  const float* lat = (const float*)d_in[3];
  const float* lon = (const float*)((in_sizes[4]==180)? d_in[4] : d_in[5]);
  const float* cm_gn_w = (const float*)d_in[7];
  const float* cm_gn_b = (const float*)d_in[8];
  const float* cm_w1   = (const float*)d_in[9];
  const float* cm_b1   = (const float*)d_in[10];
  const float* cm_w2   = (const float*)d_in[11];
  const float* cm_b2   = (const float*)d_in[12];
  const float* tl_in_w = (const float*)d_in[13];
  const float* tl_ln_w = (const float*)d_in[14];
  const float* tl_ln_b = (const float*)d_in[15];
  const float* tl_w1   = (const float*)d_in[16];
  const float* tl_b1   = (const float*)d_in[17];
  const float* tl_w2   = (const float*)d_in[18];
  const float* tl_b2   = (const float*)d_in[19];
  const float* ta_in_w = (const float*)d_in[20];
  const float* ta_ln_w = (const float*)d_in[21];
  const float* ta_ln_b = (const float*)d_in[22];
  const float* ta_w1   = (const float*)d_in[23];
  const float* ta_b1   = (const float*)d_in[24];
  const float* ta_w2   = (const float*)d_in[25];
  const float* ta_b2   = (const float*)d_in[26];
  const float* klong_wk= (const float*)d_in[27];
  const float* klat_wk = (const float*)d_in[28];
  const float* pe_long_freq = (const float*)d_in[29];
  const float* pe_long_w    = (const float*)d_in[30];
  const float* pe_lat_freq  = (const float*)d_in[31];
  const float* pe_lat_w     = (const float*)d_in[32];
  const float* mh_gn_w = (const float*)d_in[33];
  const float* mh_gn_b = (const float*)d_in[34];
  const float* mh_w    = (const float*)d_in[35];

  float* ws = (float*)d_ws;
  const size_t OFF_PART1  = 0;          // 32768 (512 blocks x 32 x 2)
  const size_t OFF_GN1    = 32768;      // 64
  const size_t OFF_WLAT   = 32896;      // 91
  const size_t OFF_MEANLON= 33024;      // 46080
  const size_t OFF_MEANLAT= 79104;      // 23296
  const size_t OFF_ULSRC  = 102400;     // 46080
  const size_t OFF_UASRC  = 148480;     // 23296
  const size_t OFF_KLKL   = 171776;     // 276480 fp32 kprojT long [1536][180]
  const size_t OFF_KLKA   = 448256;     // 139776 fp32 kprojT lat  [1536][91]
  const size_t OFF_MODUL  = 588032;     // 276480 fp32 modT long [1536][180]
  const size_t OFF_MODUA  = 864512;     // 139776 fp32 modT lat  [1536][91]
  const size_t OFF_KBL    = 1004288;    // bf16 8*96*96   -> 36864 f
  const size_t OFF_KBG    = 1041152;    // bf16 8*192*192 -> 147456 f -> ends 1188608
  const size_t OFF_PART2  = 1188608;    // 1456
  const size_t OFF_B1P    = 1190064;    // 1024
  const size_t OFF_B3     = 1191088;    // 256
  const size_t OFF_WT1    = 1191424;    // bf16 [1024][256] -> 131072 f
  const size_t OFF_WT2    = 1322496;    // bf16 [768][1024] -> 393216 f
  const size_t OFF_WT3    = 1715712;    // bf16 [256][512]  -> 65536 f -> ends 1781248
  const size_t OFF_VBF    = 1781248;    // bf16 [8][180][91][64] -> 4193280 f
  const size_t OFF_A2     = 1781248;    // bf16 [16380][512] (reuses VBF post-apply1)
  const size_t OFF_UMID   = 5974528;    // bf16 [16380][256] -> 2096640 f
  const size_t OFF_H1     = 8071168;    // bf16 16380x1024 -> 8386560 f
  const size_t OFF_U1     = 8071168;    // bf16 (reuses H1)
  const size_t OFF_A1     = 16457728;   // bf16 16380x256 -> ends 18554368 (~74 MB)

  const int NPOS = 16380;

  // 1) prep (zfill + wcvt w2 + wlat)
  prep_k<<<4513,256,0,stream>>>(cm_w2, (__bf16*)(ws+OFF_WT2), (__bf16*)(ws+OFF_KBL),
      lat, ws+OFF_WLAT);

  // 2) GN1 partials + plain bf16 cast of u_src (512 blocks), parallel final reduce
  gn1cast_k<<<512,256,0,stream>>>(u_src, (__bf16*)(ws+OFF_A1), ws+OFF_PART1, NPOS);
  gn_final_par<<<1,256,0,stream>>>(ws+OFF_PART1, ws+OFF_GN1, 512, 1.f/131040.f);

  // 3) fold GN1 into W1
  w1fix_k<<<1024,256,0,stream>>>(cm_w1, cm_b1, ws+OFF_GN1, cm_gn_w, cm_gn_b,
      (__bf16*)(ws+OFF_WT1), ws+OFF_B1P);

  // 4) h1 = gelu(A1 @ W1' + b1')  [16380 x 1024] bf16  (row-fastest grid: XCD A-reuse)
  gemm_ld<1,1><<<dim3(128,8),256,0,stream>>>((const __bf16*)(ws+OFF_A1),
      (const __bf16*)(ws+OFF_WT1), ws+OFF_B1P, ws+OFF_H1, nullptr, nullptr, NPOS, 1024, 256);

  // 5) u2 = h1 @ W2 + b2: cols<512 -> vbf bf16; cols>=512 -> umid bf16
  gemm_ld<0,2><<<dim3(128,6),256,0,stream>>>((const __bf16*)(ws+OFF_H1),
      (const __bf16*)(ws+OFF_WT2), cm_b2, nullptr, (__bf16*)(ws+OFF_VBF),
      (__bf16*)(ws+OFF_UMID), NPOS, 768, 1024);

  // 6) merged means
  means_k<<<271,256,0,stream>>>((const __bf16*)(ws+OFF_UMID), ws+OFF_MEANLON, ws+OFF_MEANLAT);

  // 7) merged pooling MLPs
  pool2_k<<<271,256,0,stream>>>(ws+OFF_MEANLON, ws+OFF_MEANLAT, ws+OFF_WLAT,
      tl_in_w, tl_ln_w, tl_ln_b, tl_w1, tl_b1, tl_w2, tl_b2,
      ta_in_w, ta_ln_w, ta_ln_b, ta_w1, ta_b1, ta_w2, ta_b2,
      ws+OFF_ULSRC, ws+OFF_UASRC);

  // 8) merged k-projections (transposed)
  rowmmT2_k<<<dim3(271,6),256,0,stream>>>(ws+OFF_ULSRC, ws+OFF_UASRC, klong_wk, klat_wk,
      ws+OFF_KLKL, ws+OFF_KLKA);

  // 9) merged modulation tables (transposed)
  modu2_k<<<2168,256,0,stream>>>(lon, lat, pe_long_freq, pe_lat_freq, pe_long_w, pe_lat_w,
      ws+OFF_MODUL, ws+OFF_MODUA);

  // 10) merged low-rank kernels -> padded bf16
  lrk2_k<<<2168,256,0,stream>>>(u_long_qry, u_lat_qry, ws+OFF_KLKL, ws+OFF_KLKA,
      ws+OFF_MODUL, ws+OFF_MODUA, ws+OFF_WLAT, (__bf16*)(ws+OFF_KBG), (__bf16*)(ws+OFF_KBL));

  // 11) kernel application (MFMA); apply2 emits bf16 A2 + GN2 partials
  apply1_mfma<<<8*180,256,0,stream>>>((const __bf16*)(ws+OFF_KBL), (const __bf16*)(ws+OFF_VBF),
      (__bf16*)(ws+OFF_U1));
  apply2_mfma<<<8*91, 256,0,stream>>>((const __bf16*)(ws+OFF_KBG), (const __bf16*)(ws+OFF_U1),
      (__bf16*)(ws+OFF_A2), ws+OFF_PART2);

  // 12) fold GN2 into mh_w (parallel stats), then final projection
  w3fix_k<<<256,256,0,stream>>>(mh_w, ws+OFF_PART2, mh_gn_w, mh_gn_b,
      (__bf16*)(ws+OFF_WT3), ws+OFF_B3);
  gemm_ld<0,0><<<dim3(128,2),256,0,stream>>>((const __bf16*)(ws+OFF_A2),
      (const __bf16*)(ws+OFF_WT3), ws+OFF_B3, (float*)d_out, nullptr, nullptr, NPOS, 256, 512);
}